// Round 1
// baseline (482.086 us; speedup 1.0000x reference)
//
#include <hip/hip_runtime.h>
#include <cstddef>

#define M_TOK 21760
#define LQ_ 5440

// ---------------------------------------------------------------------------
// Generic fp32 GEMM: out[M,N] = (Xa (+Xb))[M,256] @ W[256,N] + bias[N]
// optional relu, optional residual add (res is [M,256], only used when N==256)
// 64x64 tile, K-chunk 64, 256 threads, 4x4 micro-tile per thread.
// ---------------------------------------------------------------------------
__global__ __launch_bounds__(256) void gemm_k(
    const float* __restrict__ Xa, const float* __restrict__ Xb,
    const float* __restrict__ W, const float* __restrict__ bias,
    const float* __restrict__ res, float* __restrict__ out,
    int N, int relu)
{
  __shared__ float Xs[64][68];  // transposed: Xs[k][m]   (68 pad: rows 16B-aligned, 2-way max)
  __shared__ float Ws[64][68];  // Ws[k][n]
  const int t = threadIdx.x;
  const int tx = t & 15, ty = t >> 4;
  const int m0 = blockIdx.x * 64, n0 = blockIdx.y * 64;
  float acc[4][4] = {{0.f}};

  for (int k0 = 0; k0 < 256; k0 += 64) {
    // --- X tile: rows m0..m0+63, k k0..k0+63 -> transposed into Xs[k][m]
#pragma unroll
    for (int it = 0; it < 4; ++it) {
      const int r  = ty + (it << 4);   // 0..63 token-in-tile
      const int kk = tx << 2;          // 0..60
      const float* p = Xa + (size_t)(m0 + r) * 256 + k0 + kk;
      float4 v = *(const float4*)p;
      if (Xb) {
        float4 u = *(const float4*)(Xb + (size_t)(m0 + r) * 256 + k0 + kk);
        v.x += u.x; v.y += u.y; v.z += u.z; v.w += u.w;
      }
      Xs[kk + 0][r] = v.x; Xs[kk + 1][r] = v.y;
      Xs[kk + 2][r] = v.z; Xs[kk + 3][r] = v.w;
    }
    // --- W tile: rows k0..k0+63, cols n0..n0+63 -> Ws[k][n]
#pragma unroll
    for (int it = 0; it < 4; ++it) {
      const int kk = ty + (it << 4);
      const int nn = tx << 2;
      float4 v = *(const float4*)(W + (size_t)(k0 + kk) * N + n0 + nn);
      *(float4*)&Ws[kk][nn] = v;
    }
    __syncthreads();

#pragma unroll 16
    for (int k = 0; k < 64; ++k) {
      const float4 xv = *(const float4*)&Xs[k][ty << 2];
      const float4 wv = *(const float4*)&Ws[k][tx << 2];
      const float xr[4] = {xv.x, xv.y, xv.z, xv.w};
      const float wr[4] = {wv.x, wv.y, wv.z, wv.w};
#pragma unroll
      for (int i = 0; i < 4; ++i)
#pragma unroll
        for (int j = 0; j < 4; ++j)
          acc[i][j] = fmaf(xr[i], wr[j], acc[i][j]);
    }
    __syncthreads();
  }

#pragma unroll
  for (int i = 0; i < 4; ++i) {
    const int m = m0 + (ty << 2) + i;
#pragma unroll
    for (int j = 0; j < 4; ++j) {
      const int n = n0 + (tx << 2) + j;
      float v = acc[i][j] + bias[n];
      if (relu) v = fmaxf(v, 0.f);
      if (res) v += res[(size_t)m * 256 + n];
      out[(size_t)m * N + n] = v;
    }
  }
}

// ---------------------------------------------------------------------------
// Softmax over groups of 16 contiguous floats (per token*head), in place.
// ---------------------------------------------------------------------------
__global__ __launch_bounds__(256) void softmax16_k(float* __restrict__ a, int ngroups)
{
  const int g = blockIdx.x * 256 + threadIdx.x;
  if (g >= ngroups) return;
  float* p = a + (size_t)g * 16;
  float x[16];
#pragma unroll
  for (int i = 0; i < 4; ++i) *(float4*)&x[i * 4] = ((const float4*)p)[i];
  float mx = x[0];
#pragma unroll
  for (int i = 1; i < 16; ++i) mx = fmaxf(mx, x[i]);
  float s = 0.f;
#pragma unroll
  for (int i = 0; i < 16; ++i) { x[i] = __expf(x[i] - mx); s += x[i]; }
  const float inv = 1.f / s;
#pragma unroll
  for (int i = 0; i < 16; ++i) x[i] *= inv;
#pragma unroll
  for (int i = 0; i < 4; ++i) ((float4*)p)[i] = *(const float4*)&x[i * 4];
}

// ---------------------------------------------------------------------------
// Deformable sampling: one block per token. 128 threads precompute corner
// (weight*aw*valid, row index) into LDS; 256 threads gather over (h,d).
// ---------------------------------------------------------------------------
__global__ __launch_bounds__(256) void samp_k(
    const float* __restrict__ value, const float* __restrict__ off,
    const float* __restrict__ aw, const float* __restrict__ ref,
    float* __restrict__ attended)
{
  const int tok = blockIdx.x;
  __shared__ float sw[128][4];
  __shared__ int   sidx[128][4];
  const int t = threadIdx.x;

  if (t < 128) {
    const int lvl = (t >> 2) & 3;
    const int HW[4] = {64, 32, 16, 8};
    const int LS[4] = {0, 4096, 5120, 5376};
    const int Wl = HW[lvl], Hl = HW[lvl];
    const float fW = (float)Wl, fH = (float)Hl;
    // off col = t*2, aw col = t  (t = h*16 + lvl*4 + p)
    const float ox = off[(size_t)tok * 256 + t * 2 + 0];
    const float oy = off[(size_t)tok * 256 + t * 2 + 1];
    const float rx = ref[(size_t)tok * 8 + lvl * 2 + 0];
    const float ry = ref[(size_t)tok * 8 + lvl * 2 + 1];
    const float a  = aw[(size_t)tok * 128 + t];
    const float x = rx * fW + ox - 0.5f;
    const float y = ry * fH + oy - 0.5f;
    const float x0f = floorf(x), y0f = floorf(y);
    const float fx = x - x0f, fy = y - y0f;
    const int x0 = (int)x0f, y0 = (int)y0f;
#pragma unroll
    for (int c = 0; c < 4; ++c) {
      const int dx = c & 1, dy = c >> 1;
      const int xi = x0 + dx, yi = y0 + dy;
      const float w = (dx ? fx : 1.f - fx) * (dy ? fy : 1.f - fy);
      const bool valid = (xi >= 0) & (xi < Wl) & (yi >= 0) & (yi < Hl);
      const int xc = min(max(xi, 0), Wl - 1);
      const int yc = min(max(yi, 0), Hl - 1);
      sw[t][c]   = valid ? a * w : 0.f;
      sidx[t][c] = LS[lvl] + yc * Wl + xc;
    }
  }
  __syncthreads();

  const int h = t >> 5, d = t & 31;
  const float* vb = value + ((size_t)(tok / LQ_) * LQ_) * 256 + h * 32 + d;
  float acc = 0.f;
  for (int pp = 0; pp < 16; ++pp) {
    const int e = (h << 4) + pp;
#pragma unroll
    for (int c = 0; c < 4; ++c) {
      const float w = sw[e][c];
      const int row = sidx[e][c];
      acc = fmaf(w, vb[(size_t)row * 256], acc);
    }
  }
  attended[(size_t)tok * 256 + t] = acc;
}

// ---------------------------------------------------------------------------
// LayerNorm over 256, one wave per token (4 tokens per 256-thread block).
// ---------------------------------------------------------------------------
__global__ __launch_bounds__(256) void ln_k(
    const float* __restrict__ x, const float* __restrict__ g,
    const float* __restrict__ b, float* __restrict__ out)
{
  const int wid  = (blockIdx.x * 256 + threadIdx.x) >> 6;  // token
  const int lane = threadIdx.x & 63;
  const float4 v = *(const float4*)(x + (size_t)wid * 256 + lane * 4);
  float s = v.x + v.y + v.z + v.w;
#pragma unroll
  for (int o = 1; o < 64; o <<= 1) s += __shfl_xor(s, o);
  const float mean = s * (1.f / 256.f);
  const float dx0 = v.x - mean, dx1 = v.y - mean, dx2 = v.z - mean, dx3 = v.w - mean;
  float ss = dx0 * dx0 + dx1 * dx1 + dx2 * dx2 + dx3 * dx3;
#pragma unroll
  for (int o = 1; o < 64; o <<= 1) ss += __shfl_xor(ss, o);
  const float rstd = rsqrtf(ss * (1.f / 256.f) + 1e-5f);
  const float4 gv = *(const float4*)(g + lane * 4);
  const float4 bv = *(const float4*)(b + lane * 4);
  float4 o4;
  o4.x = dx0 * rstd * gv.x + bv.x;
  o4.y = dx1 * rstd * gv.y + bv.y;
  o4.z = dx2 * rstd * gv.z + bv.z;
  o4.w = dx3 * rstd * gv.w + bv.w;
  *(float4*)(out + (size_t)wid * 256 + lane * 4) = o4;
}

// ---------------------------------------------------------------------------
extern "C" void kernel_launch(void* const* d_in, const int* in_sizes, int n_in,
                              void* d_out, int out_size, void* d_ws, size_t ws_size,
                              hipStream_t stream)
{
  const float* src   = (const float*)d_in[0];
  const float* pos   = (const float*)d_in[1];
  const float* ref   = (const float*)d_in[2];
  // d_in[3] spatial_shapes, d_in[4] level_start_index: hardcoded constants
  const float* Wv    = (const float*)d_in[5];
  const float* bv    = (const float*)d_in[6];
  const float* Woff  = (const float*)d_in[7];
  const float* boff  = (const float*)d_in[8];
  const float* Wattn = (const float*)d_in[9];
  const float* battn = (const float*)d_in[10];
  const float* Wout  = (const float*)d_in[11];
  const float* bout  = (const float*)d_in[12];
  const float* g1    = (const float*)d_in[13];
  const float* b1    = (const float*)d_in[14];
  const float* W1    = (const float*)d_in[15];
  const float* bb1   = (const float*)d_in[16];
  const float* W2    = (const float*)d_in[17];
  const float* bb2   = (const float*)d_in[18];
  const float* g3    = (const float*)d_in[19];
  const float* b3    = (const float*)d_in[20];

  float* out = (float*)d_out;
  float* ws  = (float*)d_ws;
  const size_t M = M_TOK;

  float* bufA = ws;                                   // M*256  value -> r1
  float* bufB = bufA + M * 256;                       // M*256  off   -> h
  float* bufC = bufB + M * 256;                       // M*128  attn logits -> aw
  float* bufD = bufC + M * 128;                       // M*256  attended -> r2
  float* bufE = bufD + M * 256;                       // M*256  sxy

  const dim3 blk(256);

  // value = src @ Wv + bv
  gemm_k<<<dim3(340, 4), blk, 0, stream>>>(src, nullptr, Wv, bv, nullptr, bufA, 256, 0);
  // off = (src+pos) @ Woff + boff
  gemm_k<<<dim3(340, 4), blk, 0, stream>>>(src, pos, Woff, boff, nullptr, bufB, 256, 0);
  // attn logits = (src+pos) @ Wattn + battn
  gemm_k<<<dim3(340, 2), blk, 0, stream>>>(src, pos, Wattn, battn, nullptr, bufC, 128, 0);
  // softmax over 16 per (token, head)
  softmax16_k<<<(M_TOK * 8 + 255) / 256, blk, 0, stream>>>(bufC, M_TOK * 8);
  // deformable bilinear sampling -> attended
  samp_k<<<M_TOK, blk, 0, stream>>>(bufA, bufB, bufC, ref, bufD);
  // r1 = attended @ Wout + bout + src
  gemm_k<<<dim3(340, 4), blk, 0, stream>>>(bufD, nullptr, Wout, bout, src, bufA, 256, 0);
  // sxy = LN(r1; g1,b1)
  ln_k<<<5440, blk, 0, stream>>>(bufA, g1, b1, bufE);
  // h = relu(sxy @ W1 + bb1)
  gemm_k<<<dim3(340, 4), blk, 0, stream>>>(bufE, nullptr, W1, bb1, nullptr, bufB, 256, 1);
  // r2 = h @ W2 + bb2 + sxy
  gemm_k<<<dim3(340, 4), blk, 0, stream>>>(bufB, nullptr, W2, bb2, bufE, bufD, 256, 0);
  // out = LN(r2; g3,b3)
  ln_k<<<5440, blk, 0, stream>>>(bufD, g3, b3, out);
}

// Round 2
// 201.965 us; speedup vs baseline: 2.3870x; 2.3870x over previous
//
#include <hip/hip_runtime.h>
#include <cstddef>
#include <cstdint>

#define M_TOK 21760
#define LQ_ 5440

typedef __bf16 bf16x8 __attribute__((ext_vector_type(8)));
typedef float f32x4v __attribute__((ext_vector_type(4)));

__device__ __forceinline__ unsigned short f2bf(float f) {
  unsigned u = __builtin_bit_cast(unsigned, f);
  unsigned r = u + 0x7fffu + ((u >> 16) & 1u);
  return (unsigned short)(r >> 16);
}

// ---------------------------------------------------------------------------
// prep_x: s16 = bf16(src), q16 = bf16(src+pos)   (vectorized float4)
// ---------------------------------------------------------------------------
__global__ __launch_bounds__(256) void prep_x(
    const float* __restrict__ src, const float* __restrict__ pos,
    unsigned short* __restrict__ s16, unsigned short* __restrict__ q16)
{
  const int i = blockIdx.x * 256 + threadIdx.x;  // float4 index, grid exact
  const float4 s = ((const float4*)src)[i];
  const float4 p = ((const float4*)pos)[i];
  ushort4 a, b;
  a.x = f2bf(s.x); a.y = f2bf(s.y); a.z = f2bf(s.z); a.w = f2bf(s.w);
  b.x = f2bf(s.x + p.x); b.y = f2bf(s.y + p.y); b.z = f2bf(s.z + p.z); b.w = f2bf(s.w + p.w);
  ((ushort4*)s16)[i] = a;
  ((ushort4*)q16)[i] = b;
}

// ---------------------------------------------------------------------------
// prep_w: cast + transpose all 6 weights into Wt[n][k] bf16, packed in G.
// out elem offsets: Wv 0, Woff 65536, Wattn 131072(size 32768), Wout 163840,
// W1 229376, W2 294912; total 360448 elems. grid = 1408 * 256 exact.
// ---------------------------------------------------------------------------
__global__ __launch_bounds__(256) void prep_w(
    const float* __restrict__ Wv, const float* __restrict__ Woff,
    const float* __restrict__ Wattn, const float* __restrict__ Wout,
    const float* __restrict__ W1, const float* __restrict__ W2,
    unsigned short* __restrict__ G)
{
  const int gid = blockIdx.x * 256 + threadIdx.x;
  const float* srcs[6] = {Wv, Woff, Wattn, Wout, W1, W2};
  const int starts[7] = {0, 65536, 131072, 163840, 229376, 294912, 360448};
  const int Nn[6] = {256, 256, 128, 256, 256, 256};
  int m = 0;
#pragma unroll
  for (int i = 1; i < 6; ++i) m += (gid >= starts[i]);
  const int local = gid - starts[m];
  const int n = local >> 8;        // K = 256
  const int k = local & 255;
  G[gid] = f2bf(srcs[m][(size_t)k * Nn[m] + n]);
}

// ---------------------------------------------------------------------------
// bf16 MFMA GEMM: out[M,N] = A16[M,256] @ W[256,N] (Wt given as [N][256] bf16)
// 128x128 tile, BK=64, 256 thr = 4 waves (2x2 of 64x64), 16x16x32 MFMA.
// global_load_lds width 16 into linear LDS; XOR-swizzled source + reads.
// ---------------------------------------------------------------------------
__global__ __launch_bounds__(256, 2) void gemm_bf16_k(
    const unsigned short* __restrict__ A, const unsigned short* __restrict__ Wt,
    const float* __restrict__ bias, const float* __restrict__ res,
    float* __restrict__ outf, unsigned short* __restrict__ out16,
    int N, int relu)
{
  __shared__ unsigned short As[128 * 64];  // [row][k] physical, swizzled, 16 KB
  __shared__ unsigned short Bs[128 * 64];  // [n][k]
  const int t = threadIdx.x;
  const int lane = t & 63, wave = t >> 6;
  const int wm = wave >> 1, wn = wave & 1;
  const int m0 = blockIdx.x * 128, n0 = blockIdx.y * 128;

  const int lrow = lane >> 3;               // row-in-8
  const int pcol = (lane & 7) << 4;         // physical byte col
  const int scol = pcol ^ (lrow << 4);      // swizzled (logical) byte col

  f32x4v acc[4][4];
#pragma unroll
  for (int i = 0; i < 4; ++i)
#pragma unroll
    for (int j = 0; j < 4; ++j) acc[i][j] = (f32x4v){0.f, 0.f, 0.f, 0.f};

  const int fr = lane & 15;
  const int fkb = (lane >> 4) << 4;         // byte offset of this lane's 8-bf16 group

  for (int k0 = 0; k0 < 256; k0 += 64) {
#pragma unroll
    for (int i = 0; i < 4; ++i) {
      const int row = wave * 32 + i * 8 + lrow;
      const unsigned short* g = A + (size_t)(m0 + row) * 256 + k0 + (scol >> 1);
      unsigned short* s = As + (wave * 32 + i * 8) * 64;
      __builtin_amdgcn_global_load_lds(
          (const __attribute__((address_space(1))) void*)g,
          (__attribute__((address_space(3))) void*)s, 16, 0, 0);
    }
#pragma unroll
    for (int i = 0; i < 4; ++i) {
      const int row = wave * 32 + i * 8 + lrow;  // n index
      const unsigned short* g = Wt + (size_t)(n0 + row) * 256 + k0 + (scol >> 1);
      unsigned short* s = Bs + (wave * 32 + i * 8) * 64;
      __builtin_amdgcn_global_load_lds(
          (const __attribute__((address_space(1))) void*)g,
          (__attribute__((address_space(3))) void*)s, 16, 0, 0);
    }
    __syncthreads();

    bf16x8 af[4][2], bfr[4][2];
#pragma unroll
    for (int i = 0; i < 4; ++i) {
      const int row = wm * 64 + i * 16 + fr;
      const char* base = (const char*)As + row * 128;
#pragma unroll
      for (int kk = 0; kk < 2; ++kk) {
        const int colb = (kk * 64 + fkb) ^ ((row & 7) << 4);
        af[i][kk] = *(const bf16x8*)(base + colb);
      }
    }
#pragma unroll
    for (int j = 0; j < 4; ++j) {
      const int row = wn * 64 + j * 16 + fr;
      const char* base = (const char*)Bs + row * 128;
#pragma unroll
      for (int kk = 0; kk < 2; ++kk) {
        const int colb = (kk * 64 + fkb) ^ ((row & 7) << 4);
        bfr[j][kk] = *(const bf16x8*)(base + colb);
      }
    }
#pragma unroll
    for (int i = 0; i < 4; ++i)
#pragma unroll
      for (int j = 0; j < 4; ++j) {
        acc[i][j] = __builtin_amdgcn_mfma_f32_16x16x32_bf16(af[i][0], bfr[j][0], acc[i][j], 0, 0, 0);
        acc[i][j] = __builtin_amdgcn_mfma_f32_16x16x32_bf16(af[i][1], bfr[j][1], acc[i][j], 0, 0, 0);
      }
    __syncthreads();
  }

  const int fq = lane >> 4;
#pragma unroll
  for (int j = 0; j < 4; ++j) {
    const int n = n0 + wn * 64 + j * 16 + fr;
    const float bj = bias[n];
#pragma unroll
    for (int i = 0; i < 4; ++i) {
#pragma unroll
      for (int r = 0; r < 4; ++r) {
        const int m = m0 + wm * 64 + i * 16 + fq * 4 + r;
        float v = acc[i][j][r] + bj;
        if (relu) v = fmaxf(v, 0.f);
        if (res) v += res[(size_t)m * 256 + n];
        if (outf) outf[(size_t)m * N + n] = v;
        if (out16) out16[(size_t)m * N + n] = f2bf(v);
      }
    }
  }
}

// ---------------------------------------------------------------------------
// Softmax over groups of 16 contiguous floats, in place.
// ---------------------------------------------------------------------------
__global__ __launch_bounds__(256) void softmax16_k(float* __restrict__ a, int ngroups)
{
  const int g = blockIdx.x * 256 + threadIdx.x;
  if (g >= ngroups) return;
  float* p = a + (size_t)g * 16;
  float x[16];
#pragma unroll
  for (int i = 0; i < 4; ++i) *(float4*)&x[i * 4] = ((const float4*)p)[i];
  float mx = x[0];
#pragma unroll
  for (int i = 1; i < 16; ++i) mx = fmaxf(mx, x[i]);
  float s = 0.f;
#pragma unroll
  for (int i = 0; i < 16; ++i) { x[i] = __expf(x[i] - mx); s += x[i]; }
  const float inv = 1.f / s;
#pragma unroll
  for (int i = 0; i < 16; ++i) x[i] *= inv;
#pragma unroll
  for (int i = 0; i < 4; ++i) ((float4*)p)[i] = *(const float4*)&x[i * 4];
}

// ---------------------------------------------------------------------------
// Deformable sampling: 4 tokens per block, float4 gathers, bf16 output.
// LDS layout [ti][pp*8+h][c] so the 8 h-lanes hit 8 distinct 16B slots.
// ---------------------------------------------------------------------------
__global__ __launch_bounds__(256) void samp_k(
    const float* __restrict__ value, const float* __restrict__ off,
    const float* __restrict__ aw, const float* __restrict__ ref,
    unsigned short* __restrict__ att16)
{
  const int tok0 = blockIdx.x * 4;
  __shared__ float sw[4][128][4];
  __shared__ int   sidx[4][128][4];
  const int t = threadIdx.x;

#pragma unroll
  for (int e2 = 0; e2 < 2; ++e2) {
    const int idx = (e2 << 8) + t;         // 0..511
    const int ti = idx >> 7;
    const int e  = idx & 127;              // h*16 + lvl*4 + p
    const int tok = tok0 + ti;
    const int h = e >> 4;
    const int lvl = (e >> 2) & 3;
    const int es = ((e & 15) << 3) | h;    // pp*8 + h
    const int HW[4] = {64, 32, 16, 8};
    const int LS[4] = {0, 4096, 5120, 5376};
    const int Wl = HW[lvl], Hl = HW[lvl];
    const float ox = off[(size_t)tok * 256 + e * 2 + 0];
    const float oy = off[(size_t)tok * 256 + e * 2 + 1];
    const float rx = ref[(size_t)tok * 8 + lvl * 2 + 0];
    const float ry = ref[(size_t)tok * 8 + lvl * 2 + 1];
    const float a  = aw[(size_t)tok * 128 + e];
    const float x = rx * (float)Wl + ox - 0.5f;
    const float y = ry * (float)Hl + oy - 0.5f;
    const float x0f = floorf(x), y0f = floorf(y);
    const float fx = x - x0f, fy = y - y0f;
    const int x0 = (int)x0f, y0 = (int)y0f;
#pragma unroll
    for (int c = 0; c < 4; ++c) {
      const int dx = c & 1, dy = c >> 1;
      const int xi = x0 + dx, yi = y0 + dy;
      const float w = (dx ? fx : 1.f - fx) * (dy ? fy : 1.f - fy);
      const bool valid = (xi >= 0) & (xi < Wl) & (yi >= 0) & (yi < Hl);
      const int xc = min(max(xi, 0), Wl - 1);
      const int yc = min(max(yi, 0), Hl - 1);
      sw[ti][es][c]   = valid ? a * w : 0.f;
      sidx[ti][es][c] = LS[lvl] + yc * Wl + xc;
    }
  }
  __syncthreads();

  const int ti = t >> 6, l = t & 63;
  const int h = l >> 3, d4 = (l & 7) << 2;
  const int tok = tok0 + ti;
  const float* vb = value + (size_t)((tok / LQ_) * LQ_) * 256 + h * 32 + d4;
  float4 acc = {0.f, 0.f, 0.f, 0.f};
  for (int pp = 0; pp < 16; ++pp) {
    const int es = (pp << 3) | h;
    const float4 w4 = *(const float4*)&sw[ti][es][0];
    const int4  i4  = *(const int4*)&sidx[ti][es][0];
    const float4 v0 = *(const float4*)(vb + (size_t)i4.x * 256);
    const float4 v1 = *(const float4*)(vb + (size_t)i4.y * 256);
    const float4 v2 = *(const float4*)(vb + (size_t)i4.z * 256);
    const float4 v3 = *(const float4*)(vb + (size_t)i4.w * 256);
    acc.x = fmaf(w4.x, v0.x, acc.x); acc.y = fmaf(w4.x, v0.y, acc.y);
    acc.z = fmaf(w4.x, v0.z, acc.z); acc.w = fmaf(w4.x, v0.w, acc.w);
    acc.x = fmaf(w4.y, v1.x, acc.x); acc.y = fmaf(w4.y, v1.y, acc.y);
    acc.z = fmaf(w4.y, v1.z, acc.z); acc.w = fmaf(w4.y, v1.w, acc.w);
    acc.x = fmaf(w4.z, v2.x, acc.x); acc.y = fmaf(w4.z, v2.y, acc.y);
    acc.z = fmaf(w4.z, v2.z, acc.z); acc.w = fmaf(w4.z, v2.w, acc.w);
    acc.x = fmaf(w4.w, v3.x, acc.x); acc.y = fmaf(w4.w, v3.y, acc.y);
    acc.z = fmaf(w4.w, v3.z, acc.z); acc.w = fmaf(w4.w, v3.w, acc.w);
  }
  ushort4 o;
  o.x = f2bf(acc.x); o.y = f2bf(acc.y); o.z = f2bf(acc.z); o.w = f2bf(acc.w);
  *(ushort4*)(att16 + (size_t)tok * 256 + h * 32 + d4) = o;
}

// ---------------------------------------------------------------------------
// LayerNorm over 256, one wave per token; optional secondary bf16 output.
// ---------------------------------------------------------------------------
__global__ __launch_bounds__(256) void ln_k(
    const float* __restrict__ x, const float* __restrict__ g,
    const float* __restrict__ b, float* __restrict__ outf,
    unsigned short* __restrict__ out16)
{
  const int wid  = (blockIdx.x * 256 + threadIdx.x) >> 6;
  const int lane = threadIdx.x & 63;
  const float4 v = *(const float4*)(x + (size_t)wid * 256 + lane * 4);
  float s = v.x + v.y + v.z + v.w;
#pragma unroll
  for (int o = 1; o < 64; o <<= 1) s += __shfl_xor(s, o);
  const float mean = s * (1.f / 256.f);
  const float dx0 = v.x - mean, dx1 = v.y - mean, dx2 = v.z - mean, dx3 = v.w - mean;
  float ss = dx0 * dx0 + dx1 * dx1 + dx2 * dx2 + dx3 * dx3;
#pragma unroll
  for (int o = 1; o < 64; o <<= 1) ss += __shfl_xor(ss, o);
  const float rstd = rsqrtf(ss * (1.f / 256.f) + 1e-5f);
  const float4 gv = *(const float4*)(g + lane * 4);
  const float4 bv = *(const float4*)(b + lane * 4);
  float4 o4;
  o4.x = dx0 * rstd * gv.x + bv.x;
  o4.y = dx1 * rstd * gv.y + bv.y;
  o4.z = dx2 * rstd * gv.z + bv.z;
  o4.w = dx3 * rstd * gv.w + bv.w;
  if (outf) *(float4*)(outf + (size_t)wid * 256 + lane * 4) = o4;
  if (out16) {
    ushort4 o;
    o.x = f2bf(o4.x); o.y = f2bf(o4.y); o.z = f2bf(o4.z); o.w = f2bf(o4.w);
    *(ushort4*)(out16 + (size_t)wid * 256 + lane * 4) = o;
  }
}

// ---------------------------------------------------------------------------
extern "C" void kernel_launch(void* const* d_in, const int* in_sizes, int n_in,
                              void* d_out, int out_size, void* d_ws, size_t ws_size,
                              hipStream_t stream)
{
  const float* src   = (const float*)d_in[0];
  const float* pos   = (const float*)d_in[1];
  const float* ref   = (const float*)d_in[2];
  const float* Wv    = (const float*)d_in[5];
  const float* bv    = (const float*)d_in[6];
  const float* Woff  = (const float*)d_in[7];
  const float* boff  = (const float*)d_in[8];
  const float* Wattn = (const float*)d_in[9];
  const float* battn = (const float*)d_in[10];
  const float* Wout  = (const float*)d_in[11];
  const float* bout  = (const float*)d_in[12];
  const float* g1    = (const float*)d_in[13];
  const float* b1    = (const float*)d_in[14];
  const float* W1    = (const float*)d_in[15];
  const float* bb1   = (const float*)d_in[16];
  const float* W2    = (const float*)d_in[17];
  const float* bb2   = (const float*)d_in[18];
  const float* g3    = (const float*)d_in[19];
  const float* b3    = (const float*)d_in[20];

  float* out = (float*)d_out;
  char* ws = (char*)d_ws;
  const size_t M = M_TOK;
  const size_t SZF = M * 256 * 4;       // 22,282,240 B

  float* bufA = (float*)(ws);                    // value -> sxy
  float* bufB = (float*)(ws + SZF);              // off -> r1 -> r2
  float* bufC = (float*)(ws + 2 * SZF);          // logits/aw  (M*128 f32)
  unsigned short* bufE = (unsigned short*)(ws + 2 * SZF + M * 128 * 4);  // s16 -> att16 -> h16
  unsigned short* bufF = bufE + M * 256;         // q16 -> sxy16
  unsigned short* bufG = bufF + M * 256;         // transposed bf16 weights

  unsigned short* WvT    = bufG + 0;
  unsigned short* WoffT  = bufG + 65536;
  unsigned short* WattnT = bufG + 131072;
  unsigned short* WoutT  = bufG + 163840;
  unsigned short* W1T    = bufG + 229376;
  unsigned short* W2T    = bufG + 294912;

  const dim3 blk(256);

  prep_x<<<dim3(5440), blk, 0, stream>>>(src, pos, bufE, bufF);
  prep_w<<<dim3(1408), blk, 0, stream>>>(Wv, Woff, Wattn, Wout, W1, W2, bufG);

  // value = src @ Wv + bv
  gemm_bf16_k<<<dim3(170, 2), blk, 0, stream>>>(bufE, WvT, bv, nullptr, bufA, nullptr, 256, 0);
  // off = q @ Woff + boff
  gemm_bf16_k<<<dim3(170, 2), blk, 0, stream>>>(bufF, WoffT, boff, nullptr, bufB, nullptr, 256, 0);
  // logits = q @ Wattn + battn
  gemm_bf16_k<<<dim3(170, 1), blk, 0, stream>>>(bufF, WattnT, battn, nullptr, bufC, nullptr, 128, 0);
  // softmax over 16 per (token, head)
  softmax16_k<<<dim3(680), blk, 0, stream>>>(bufC, M_TOK * 8);
  // sampling -> att16 (bf16) in bufE
  samp_k<<<dim3(5440), blk, 0, stream>>>(bufA, bufB, bufC, ref, bufE);
  // r1 = att @ Wout + bout + src   -> bufB
  gemm_bf16_k<<<dim3(170, 2), blk, 0, stream>>>(bufE, WoutT, bout, src, bufB, nullptr, 256, 0);
  // sxy = LN(r1) -> bufA (f32) + bufF (bf16)
  ln_k<<<dim3(5440), blk, 0, stream>>>(bufB, g1, b1, bufA, bufF);
  // h = relu(sxy @ W1 + bb1) -> bufE (bf16 only)
  gemm_bf16_k<<<dim3(170, 2), blk, 0, stream>>>(bufF, W1T, bb1, nullptr, nullptr, bufE, 256, 1);
  // r2 = h @ W2 + bb2 + sxy -> bufB
  gemm_bf16_k<<<dim3(170, 2), blk, 0, stream>>>(bufE, W2T, bb2, bufA, bufB, nullptr, 256, 0);
  // out = LN(r2)
  ln_k<<<dim3(5440), blk, 0, stream>>>(bufB, g3, b3, out, nullptr);
}

// Round 3
// 169.066 us; speedup vs baseline: 2.8515x; 1.1946x over previous
//
#include <hip/hip_runtime.h>
#include <cstddef>
#include <cstdint>

#define M_TOK 21760
#define LQ_ 5440

typedef __bf16 bf16x8 __attribute__((ext_vector_type(8)));
typedef float f32x4v __attribute__((ext_vector_type(4)));

__device__ __forceinline__ unsigned short f2bf(float f) {
  unsigned u = __builtin_bit_cast(unsigned, f);
  unsigned r = u + 0x7fffu + ((u >> 16) & 1u);
  return (unsigned short)(r >> 16);
}
__device__ __forceinline__ float bflo(unsigned u) {  // low bf16 -> f32
  return __builtin_bit_cast(float, u << 16);
}
__device__ __forceinline__ float bfhi(unsigned u) {  // high bf16 -> f32
  return __builtin_bit_cast(float, u & 0xffff0000u);
}

// ---------------------------------------------------------------------------
// prep_x: s16 = bf16(src), q16 = bf16(src+pos)
// ---------------------------------------------------------------------------
__global__ __launch_bounds__(256) void prep_x(
    const float* __restrict__ src, const float* __restrict__ pos,
    unsigned short* __restrict__ s16, unsigned short* __restrict__ q16)
{
  const int i = blockIdx.x * 256 + threadIdx.x;
  const float4 s = ((const float4*)src)[i];
  const float4 p = ((const float4*)pos)[i];
  ushort4 a, b;
  a.x = f2bf(s.x); a.y = f2bf(s.y); a.z = f2bf(s.z); a.w = f2bf(s.w);
  b.x = f2bf(s.x + p.x); b.y = f2bf(s.y + p.y); b.z = f2bf(s.z + p.z); b.w = f2bf(s.w + p.w);
  ((ushort4*)s16)[i] = a;
  ((ushort4*)q16)[i] = b;
}

// ---------------------------------------------------------------------------
// prep_w: cast + transpose weights into Wt[n][k] bf16, packed.
// Wv 0, Woff 65536, Wattn 131072, Wout 163840, W1 229376, W2 294912 (elems)
// ---------------------------------------------------------------------------
__global__ __launch_bounds__(256) void prep_w(
    const float* __restrict__ Wv, const float* __restrict__ Woff,
    const float* __restrict__ Wattn, const float* __restrict__ Wout,
    const float* __restrict__ W1, const float* __restrict__ W2,
    unsigned short* __restrict__ G)
{
  const int gid = blockIdx.x * 256 + threadIdx.x;
  const float* srcs[6] = {Wv, Woff, Wattn, Wout, W1, W2};
  const int starts[7] = {0, 65536, 131072, 163840, 229376, 294912, 360448};
  const int Nn[6] = {256, 256, 128, 256, 256, 256};
  int m = 0;
#pragma unroll
  for (int i = 1; i < 6; ++i) m += (gid >= starts[i]);
  const int local = gid - starts[m];
  const int n = local >> 8;
  const int k = local & 255;
  G[gid] = f2bf(srcs[m][(size_t)k * Nn[m] + n]);
}

// ---------------------------------------------------------------------------
// bf16 MFMA GEMM: out[M,N] = A16[M,256] @ Wt[N,256]^T. 128x128 tile, BK=64.
// bias2 used for n>=256 tiles (fused off|attn GEMM).
// ---------------------------------------------------------------------------
__global__ __launch_bounds__(256, 2) void gemm_bf16_k(
    const unsigned short* __restrict__ A, const unsigned short* __restrict__ Wt,
    const float* __restrict__ bias, const float* __restrict__ bias2,
    const float* __restrict__ res,
    float* __restrict__ outf, unsigned short* __restrict__ out16,
    int N, int relu)
{
  __shared__ unsigned short As[128 * 64];
  __shared__ unsigned short Bs[128 * 64];
  const int t = threadIdx.x;
  const int lane = t & 63, wave = t >> 6;
  const int wm = wave >> 1, wn = wave & 1;
  const int m0 = blockIdx.x * 128, n0 = blockIdx.y * 128;

  const int lrow = lane >> 3;
  const int pcol = (lane & 7) << 4;
  const int scol = pcol ^ (lrow << 4);

  f32x4v acc[4][4];
#pragma unroll
  for (int i = 0; i < 4; ++i)
#pragma unroll
    for (int j = 0; j < 4; ++j) acc[i][j] = (f32x4v){0.f, 0.f, 0.f, 0.f};

  const int fr = lane & 15;
  const int fkb = (lane >> 4) << 4;

  for (int k0 = 0; k0 < 256; k0 += 64) {
#pragma unroll
    for (int i = 0; i < 4; ++i) {
      const int row = wave * 32 + i * 8 + lrow;
      const unsigned short* g = A + (size_t)(m0 + row) * 256 + k0 + (scol >> 1);
      unsigned short* s = As + (wave * 32 + i * 8) * 64;
      __builtin_amdgcn_global_load_lds(
          (const __attribute__((address_space(1))) void*)g,
          (__attribute__((address_space(3))) void*)s, 16, 0, 0);
    }
#pragma unroll
    for (int i = 0; i < 4; ++i) {
      const int row = wave * 32 + i * 8 + lrow;
      const unsigned short* g = Wt + (size_t)(n0 + row) * 256 + k0 + (scol >> 1);
      unsigned short* s = Bs + (wave * 32 + i * 8) * 64;
      __builtin_amdgcn_global_load_lds(
          (const __attribute__((address_space(1))) void*)g,
          (__attribute__((address_space(3))) void*)s, 16, 0, 0);
    }
    __syncthreads();

    bf16x8 af[4][2], bfr[4][2];
#pragma unroll
    for (int i = 0; i < 4; ++i) {
      const int row = wm * 64 + i * 16 + fr;
      const char* base = (const char*)As + row * 128;
#pragma unroll
      for (int kk = 0; kk < 2; ++kk) {
        const int colb = (kk * 64 + fkb) ^ ((row & 7) << 4);
        af[i][kk] = *(const bf16x8*)(base + colb);
      }
    }
#pragma unroll
    for (int j = 0; j < 4; ++j) {
      const int row = wn * 64 + j * 16 + fr;
      const char* base = (const char*)Bs + row * 128;
#pragma unroll
      for (int kk = 0; kk < 2; ++kk) {
        const int colb = (kk * 64 + fkb) ^ ((row & 7) << 4);
        bfr[j][kk] = *(const bf16x8*)(base + colb);
      }
    }
#pragma unroll
    for (int i = 0; i < 4; ++i)
#pragma unroll
      for (int j = 0; j < 4; ++j) {
        acc[i][j] = __builtin_amdgcn_mfma_f32_16x16x32_bf16(af[i][0], bfr[j][0], acc[i][j], 0, 0, 0);
        acc[i][j] = __builtin_amdgcn_mfma_f32_16x16x32_bf16(af[i][1], bfr[j][1], acc[i][j], 0, 0, 0);
      }
    __syncthreads();
  }

  const float* bsel = bias;
  int nsub = 0;
  if (bias2 && n0 >= 256) { bsel = bias2; nsub = 256; }

  const int fq = lane >> 4;
#pragma unroll
  for (int j = 0; j < 4; ++j) {
    const int n = n0 + wn * 64 + j * 16 + fr;
    const float bj = bsel[n - nsub];
#pragma unroll
    for (int i = 0; i < 4; ++i) {
#pragma unroll
      for (int r = 0; r < 4; ++r) {
        const int m = m0 + wm * 64 + i * 16 + fq * 4 + r;
        float v = acc[i][j][r] + bj;
        if (relu) v = fmaxf(v, 0.f);
        if (res) v += res[(size_t)m * 256 + n];
        if (outf) outf[(size_t)m * N + n] = v;
        if (out16) out16[(size_t)m * N + n] = f2bf(v);
      }
    }
  }
}

// ---------------------------------------------------------------------------
// Deformable sampling, v3: 8 tokens/block, bf16 value, fused softmax.
// fused = [off(256) | attn_logits(128)] f32, stride 384.
// LDS skew: entry (ti,e) at [ti][e + (e>>4)] -> banks ((h+p)%8)*4+c, 2-way max.
// Gather: 32 lanes/token, uint4 = 8 bf16 d's per lane.
// ---------------------------------------------------------------------------
__global__ __launch_bounds__(256) void samp_k(
    const unsigned short* __restrict__ value16, const float* __restrict__ fused,
    const float* __restrict__ ref, unsigned short* __restrict__ att16)
{
  const int tok0 = blockIdx.x * 8;
  __shared__ float4 swv[8][136];
  __shared__ int4   siv[8][136];
  const int t = threadIdx.x;

#pragma unroll
  for (int it = 0; it < 4; ++it) {
    const int idx = it * 256 + t;
    const int ti = idx >> 7;
    const int e  = idx & 127;              // h*16 + lvl*4 + p
    const int tok = tok0 + ti;
    const int h = e >> 4;
    const int lvl = (e >> 2) & 3;
    const int HW[4] = {64, 32, 16, 8};
    const int LS[4] = {0, 4096, 5120, 5376};
    const int Wl = HW[lvl];

    // softmax over the 16 contiguous lanes of this (ti,h)
    const float lg = fused[(size_t)tok * 384 + 256 + e];
    float mx = lg;
#pragma unroll
    for (int o = 1; o < 16; o <<= 1) mx = fmaxf(mx, __shfl_xor(mx, o, 16));
    const float ex = __expf(lg - mx);
    float sm = ex;
#pragma unroll
    for (int o = 1; o < 16; o <<= 1) sm += __shfl_xor(sm, o, 16);
    const float a = ex / sm;

    const float ox = fused[(size_t)tok * 384 + e * 2 + 0];
    const float oy = fused[(size_t)tok * 384 + e * 2 + 1];
    const float rx = ref[(size_t)tok * 8 + lvl * 2 + 0];
    const float ry = ref[(size_t)tok * 8 + lvl * 2 + 1];
    const float x = rx * (float)Wl + ox - 0.5f;
    const float y = ry * (float)Wl + oy - 0.5f;
    const float x0f = floorf(x), y0f = floorf(y);
    const float fx = x - x0f, fy = y - y0f;
    const int x0 = (int)x0f, y0 = (int)y0f;
    float4 w4; int4 i4;
    {
      const int xi0 = x0, xi1 = x0 + 1, yi0 = y0, yi1 = y0 + 1;
      const float wx0 = 1.f - fx, wx1 = fx, wy0 = 1.f - fy, wy1 = fy;
      const int xc0 = min(max(xi0, 0), Wl - 1), xc1 = min(max(xi1, 0), Wl - 1);
      const int yc0 = min(max(yi0, 0), Wl - 1), yc1 = min(max(yi1, 0), Wl - 1);
      const bool vx0 = (xi0 >= 0) & (xi0 < Wl), vx1 = (xi1 >= 0) & (xi1 < Wl);
      const bool vy0 = (yi0 >= 0) & (yi0 < Wl), vy1 = (yi1 >= 0) & (yi1 < Wl);
      w4.x = (vx0 & vy0) ? a * wx0 * wy0 : 0.f;
      w4.y = (vx1 & vy0) ? a * wx1 * wy0 : 0.f;
      w4.z = (vx0 & vy1) ? a * wx0 * wy1 : 0.f;
      w4.w = (vx1 & vy1) ? a * wx1 * wy1 : 0.f;
      i4.x = LS[lvl] + yc0 * Wl + xc0;
      i4.y = LS[lvl] + yc0 * Wl + xc1;
      i4.z = LS[lvl] + yc1 * Wl + xc0;
      i4.w = LS[lvl] + yc1 * Wl + xc1;
    }
    const int sl = e + h;   // skewed slot
    swv[ti][sl] = w4;
    siv[ti][sl] = i4;
  }
  __syncthreads();

  const int wave = t >> 6, lane = t & 63;
  const int ti = wave * 2 + (lane >> 5);
  const int h = (lane >> 2) & 7, dg = lane & 3;
  const int tok = tok0 + ti;
  const int vbase = (tok / LQ_) * LQ_;
  const unsigned short* vb = value16 + (size_t)vbase * 256 + h * 32 + dg * 8;
  float acc[8] = {0.f, 0.f, 0.f, 0.f, 0.f, 0.f, 0.f, 0.f};
  const int ebase = h * 17;

#pragma unroll 4
  for (int p = 0; p < 16; ++p) {
    const float4 w4 = swv[ti][ebase + p];
    const int4  i4 = siv[ti][ebase + p];
    const uint4 u0 = *(const uint4*)(vb + (size_t)i4.x * 256);
    const uint4 u1 = *(const uint4*)(vb + (size_t)i4.y * 256);
    const uint4 u2 = *(const uint4*)(vb + (size_t)i4.z * 256);
    const uint4 u3 = *(const uint4*)(vb + (size_t)i4.w * 256);
#define ACC4(U, W)                                            \
    acc[0] = fmaf(W, bflo(U.x), acc[0]);                      \
    acc[1] = fmaf(W, bfhi(U.x), acc[1]);                      \
    acc[2] = fmaf(W, bflo(U.y), acc[2]);                      \
    acc[3] = fmaf(W, bfhi(U.y), acc[3]);                      \
    acc[4] = fmaf(W, bflo(U.z), acc[4]);                      \
    acc[5] = fmaf(W, bfhi(U.z), acc[5]);                      \
    acc[6] = fmaf(W, bflo(U.w), acc[6]);                      \
    acc[7] = fmaf(W, bfhi(U.w), acc[7]);
    ACC4(u0, w4.x) ACC4(u1, w4.y) ACC4(u2, w4.z) ACC4(u3, w4.w)
#undef ACC4
  }

  uint4 o;
  o.x = (unsigned)f2bf(acc[0]) | ((unsigned)f2bf(acc[1]) << 16);
  o.y = (unsigned)f2bf(acc[2]) | ((unsigned)f2bf(acc[3]) << 16);
  o.z = (unsigned)f2bf(acc[4]) | ((unsigned)f2bf(acc[5]) << 16);
  o.w = (unsigned)f2bf(acc[6]) | ((unsigned)f2bf(acc[7]) << 16);
  *(uint4*)(att16 + (size_t)tok * 256 + h * 32 + dg * 8) = o;
}

// ---------------------------------------------------------------------------
// LayerNorm over 256, one wave per token; optional secondary bf16 output.
// ---------------------------------------------------------------------------
__global__ __launch_bounds__(256) void ln_k(
    const float* __restrict__ x, const float* __restrict__ g,
    const float* __restrict__ b, float* __restrict__ outf,
    unsigned short* __restrict__ out16)
{
  const int wid  = (blockIdx.x * 256 + threadIdx.x) >> 6;
  const int lane = threadIdx.x & 63;
  const float4 v = *(const float4*)(x + (size_t)wid * 256 + lane * 4);
  float s = v.x + v.y + v.z + v.w;
#pragma unroll
  for (int o = 1; o < 64; o <<= 1) s += __shfl_xor(s, o);
  const float mean = s * (1.f / 256.f);
  const float dx0 = v.x - mean, dx1 = v.y - mean, dx2 = v.z - mean, dx3 = v.w - mean;
  float ss = dx0 * dx0 + dx1 * dx1 + dx2 * dx2 + dx3 * dx3;
#pragma unroll
  for (int o = 1; o < 64; o <<= 1) ss += __shfl_xor(ss, o);
  const float rstd = rsqrtf(ss * (1.f / 256.f) + 1e-5f);
  const float4 gv = *(const float4*)(g + lane * 4);
  const float4 bv = *(const float4*)(b + lane * 4);
  float4 o4;
  o4.x = dx0 * rstd * gv.x + bv.x;
  o4.y = dx1 * rstd * gv.y + bv.y;
  o4.z = dx2 * rstd * gv.z + bv.z;
  o4.w = dx3 * rstd * gv.w + bv.w;
  if (outf) *(float4*)(outf + (size_t)wid * 256 + lane * 4) = o4;
  if (out16) {
    ushort4 o;
    o.x = f2bf(o4.x); o.y = f2bf(o4.y); o.z = f2bf(o4.z); o.w = f2bf(o4.w);
    *(ushort4*)(out16 + (size_t)wid * 256 + lane * 4) = o;
  }
}

// ---------------------------------------------------------------------------
extern "C" void kernel_launch(void* const* d_in, const int* in_sizes, int n_in,
                              void* d_out, int out_size, void* d_ws, size_t ws_size,
                              hipStream_t stream)
{
  const float* src   = (const float*)d_in[0];
  const float* pos   = (const float*)d_in[1];
  const float* ref   = (const float*)d_in[2];
  const float* Wv    = (const float*)d_in[5];
  const float* bv    = (const float*)d_in[6];
  const float* Woff  = (const float*)d_in[7];
  const float* boff  = (const float*)d_in[8];
  const float* Wattn = (const float*)d_in[9];
  const float* battn = (const float*)d_in[10];
  const float* Wout  = (const float*)d_in[11];
  const float* bout  = (const float*)d_in[12];
  const float* g1    = (const float*)d_in[13];
  const float* b1    = (const float*)d_in[14];
  const float* W1    = (const float*)d_in[15];
  const float* bb1   = (const float*)d_in[16];
  const float* W2    = (const float*)d_in[17];
  const float* bb2   = (const float*)d_in[18];
  const float* g3    = (const float*)d_in[19];
  const float* b3    = (const float*)d_in[20];

  float* out = (float*)d_out;
  char* ws = (char*)d_ws;
  const size_t M = M_TOK;

  float* bufA = (float*)ws;                              // f32 M*256 (sxy); first half doubles as value16
  float* bufB = (float*)(ws + M * 256 * 4);              // f32 M*384 (fused off|attn, r1, r2)
  unsigned short* bufE = (unsigned short*)(ws + M * 256 * 4 + M * 384 * 4);  // bf16 M*256: s16 -> att16 -> h16
  unsigned short* bufF = bufE + M * 256;                 // bf16 M*256: q16 -> sxy16
  unsigned short* bufG = bufF + M * 256;                 // bf16 weights (360448)
  unsigned short* value16 = (unsigned short*)bufA;       // bf16 M*256 (disjoint lifetime vs sxy)

  unsigned short* WvT     = bufG + 0;
  unsigned short* WfusedT = bufG + 65536;   // [Woff(256) | Wattn(128)] rows, K=256
  unsigned short* WoutT   = bufG + 163840;
  unsigned short* W1T     = bufG + 229376;
  unsigned short* W2T     = bufG + 294912;

  const dim3 blk(256);

  prep_x<<<dim3(5440), blk, 0, stream>>>(src, pos, bufE, bufF);
  prep_w<<<dim3(1408), blk, 0, stream>>>(Wv, Woff, Wattn, Wout, W1, W2, bufG);

  // value16 = bf16(src @ Wv + bv)
  gemm_bf16_k<<<dim3(170, 2), blk, 0, stream>>>(bufE, WvT, bv, nullptr, nullptr, nullptr, value16, 256, 0);
  // fused = q @ [Woff|Wattn] + [boff|battn]  (f32, stride 384)
  gemm_bf16_k<<<dim3(170, 3), blk, 0, stream>>>(bufF, WfusedT, boff, battn, nullptr, bufB, nullptr, 384, 0);
  // sampling (with in-kernel softmax) -> att16 in bufE
  samp_k<<<dim3(2720), blk, 0, stream>>>(value16, bufB, ref, bufE);
  // r1 = att @ Wout + bout + src -> bufB (f32, stride 256)
  gemm_bf16_k<<<dim3(170, 2), blk, 0, stream>>>(bufE, WoutT, bout, nullptr, src, bufB, nullptr, 256, 0);
  // sxy = LN(r1) -> bufA f32 + bufF bf16
  ln_k<<<dim3(5440), blk, 0, stream>>>(bufB, g1, b1, bufA, bufF);
  // h16 = bf16(relu(sxy @ W1 + bb1)) -> bufE
  gemm_bf16_k<<<dim3(170, 2), blk, 0, stream>>>(bufF, W1T, bb1, nullptr, nullptr, nullptr, bufE, 256, 1);
  // r2 = h @ W2 + bb2 + sxy -> bufB
  gemm_bf16_k<<<dim3(170, 2), blk, 0, stream>>>(bufE, W2T, bb2, nullptr, bufA, bufB, nullptr, 256, 0);
  // out = LN(r2)
  ln_k<<<dim3(5440), blk, 0, stream>>>(bufB, g3, b3, out, nullptr);
}

// Round 4
// 144.168 us; speedup vs baseline: 3.3439x; 1.1727x over previous
//
#include <hip/hip_runtime.h>
#include <cstddef>
#include <cstdint>

#define M_TOK 21760
#define LQ_ 5440

typedef __bf16 bf16x8 __attribute__((ext_vector_type(8)));
typedef float f32x4v __attribute__((ext_vector_type(4)));
typedef _Float16 half4v __attribute__((ext_vector_type(4)));
typedef short short4v __attribute__((ext_vector_type(4)));

__device__ __forceinline__ unsigned short f2bf(float f) {
  unsigned u = __builtin_bit_cast(unsigned, f);
  unsigned r = u + 0x7fffu + ((u >> 16) & 1u);
  return (unsigned short)(r >> 16);
}
__device__ __forceinline__ float bflo(unsigned u) {
  return __builtin_bit_cast(float, u << 16);
}
__device__ __forceinline__ float bfhi(unsigned u) {
  return __builtin_bit_cast(float, u & 0xffff0000u);
}

// ---------------------------------------------------------------------------
// prep_x: s16 = bf16(src), q16 = bf16(src+pos)
// ---------------------------------------------------------------------------
__global__ __launch_bounds__(256) void prep_x(
    const float* __restrict__ src, const float* __restrict__ pos,
    unsigned short* __restrict__ s16, unsigned short* __restrict__ q16)
{
  const int i = blockIdx.x * 256 + threadIdx.x;
  const float4 s = ((const float4*)src)[i];
  const float4 p = ((const float4*)pos)[i];
  ushort4 a, b;
  a.x = f2bf(s.x); a.y = f2bf(s.y); a.z = f2bf(s.z); a.w = f2bf(s.w);
  b.x = f2bf(s.x + p.x); b.y = f2bf(s.y + p.y); b.z = f2bf(s.z + p.z); b.w = f2bf(s.w + p.w);
  ((ushort4*)s16)[i] = a;
  ((ushort4*)q16)[i] = b;
}

// ---------------------------------------------------------------------------
// prep_w: cast + transpose weights into Wt[n][k] bf16, packed.
// ---------------------------------------------------------------------------
__global__ __launch_bounds__(256) void prep_w(
    const float* __restrict__ Wv, const float* __restrict__ Woff,
    const float* __restrict__ Wattn, const float* __restrict__ Wout,
    const float* __restrict__ W1, const float* __restrict__ W2,
    unsigned short* __restrict__ G)
{
  const int gid = blockIdx.x * 256 + threadIdx.x;
  const float* srcs[6] = {Wv, Woff, Wattn, Wout, W1, W2};
  const int starts[7] = {0, 65536, 131072, 163840, 229376, 294912, 360448};
  const int Nn[6] = {256, 256, 128, 256, 256, 256};
  int m = 0;
#pragma unroll
  for (int i = 1; i < 6; ++i) m += (gid >= starts[i]);
  const int local = gid - starts[m];
  const int n = local >> 8;
  const int k = local & 255;
  G[gid] = f2bf(srcs[m][(size_t)k * Nn[m] + n]);
}

// ---------------------------------------------------------------------------
// bf16 MFMA GEMM (no LN): out[M,N] = A16 @ Wt^T. 128x128 tile, BK=64.
// ---------------------------------------------------------------------------
__global__ __launch_bounds__(256, 2) void gemm_bf16_k(
    const unsigned short* __restrict__ A, const unsigned short* __restrict__ Wt,
    const float* __restrict__ bias, const float* __restrict__ bias2,
    float* __restrict__ outf, unsigned short* __restrict__ out16,
    int N, int relu)
{
  __shared__ unsigned short As[128 * 64];
  __shared__ unsigned short Bs[128 * 64];
  const int t = threadIdx.x;
  const int lane = t & 63, wave = t >> 6;
  const int wm = wave >> 1, wn = wave & 1;
  const int m0 = blockIdx.x * 128, n0 = blockIdx.y * 128;

  const int lrow = lane >> 3;
  const int pcol = (lane & 7) << 4;
  const int scol = pcol ^ (lrow << 4);

  f32x4v acc[4][4];
#pragma unroll
  for (int i = 0; i < 4; ++i)
#pragma unroll
    for (int j = 0; j < 4; ++j) acc[i][j] = (f32x4v){0.f, 0.f, 0.f, 0.f};

  const int fr = lane & 15;
  const int fkb = (lane >> 4) << 4;

  for (int k0 = 0; k0 < 256; k0 += 64) {
#pragma unroll
    for (int i = 0; i < 4; ++i) {
      const int row = wave * 32 + i * 8 + lrow;
      const unsigned short* g = A + (size_t)(m0 + row) * 256 + k0 + (scol >> 1);
      unsigned short* s = As + (wave * 32 + i * 8) * 64;
      __builtin_amdgcn_global_load_lds(
          (const __attribute__((address_space(1))) void*)g,
          (__attribute__((address_space(3))) void*)s, 16, 0, 0);
    }
#pragma unroll
    for (int i = 0; i < 4; ++i) {
      const int row = wave * 32 + i * 8 + lrow;
      const unsigned short* g = Wt + (size_t)(n0 + row) * 256 + k0 + (scol >> 1);
      unsigned short* s = Bs + (wave * 32 + i * 8) * 64;
      __builtin_amdgcn_global_load_lds(
          (const __attribute__((address_space(1))) void*)g,
          (__attribute__((address_space(3))) void*)s, 16, 0, 0);
    }
    __syncthreads();

    bf16x8 af[4][2], bfr[4][2];
#pragma unroll
    for (int i = 0; i < 4; ++i) {
      const int row = wm * 64 + i * 16 + fr;
      const char* base = (const char*)As + row * 128;
#pragma unroll
      for (int kk = 0; kk < 2; ++kk) {
        const int colb = (kk * 64 + fkb) ^ ((row & 7) << 4);
        af[i][kk] = *(const bf16x8*)(base + colb);
      }
    }
#pragma unroll
    for (int j = 0; j < 4; ++j) {
      const int row = wn * 64 + j * 16 + fr;
      const char* base = (const char*)Bs + row * 128;
#pragma unroll
      for (int kk = 0; kk < 2; ++kk) {
        const int colb = (kk * 64 + fkb) ^ ((row & 7) << 4);
        bfr[j][kk] = *(const bf16x8*)(base + colb);
      }
    }
#pragma unroll
    for (int i = 0; i < 4; ++i)
#pragma unroll
      for (int j = 0; j < 4; ++j) {
        acc[i][j] = __builtin_amdgcn_mfma_f32_16x16x32_bf16(af[i][0], bfr[j][0], acc[i][j], 0, 0, 0);
        acc[i][j] = __builtin_amdgcn_mfma_f32_16x16x32_bf16(af[i][1], bfr[j][1], acc[i][j], 0, 0, 0);
      }
    __syncthreads();
  }

  const float* bsel = bias;
  int nsub = 0;
  if (bias2 && n0 >= 256) { bsel = bias2; nsub = 256; }

  const int fq = lane >> 4;
#pragma unroll
  for (int j = 0; j < 4; ++j) {
    const int n = n0 + wn * 64 + j * 16 + fr;
    const float bj = bsel[n - nsub];
#pragma unroll
    for (int i = 0; i < 4; ++i) {
#pragma unroll
      for (int r = 0; r < 4; ++r) {
        const int m = m0 + wm * 64 + i * 16 + fq * 4 + r;
        float v = acc[i][j][r] + bj;
        if (relu) v = fmaxf(v, 0.f);
        if (outf) outf[(size_t)m * N + n] = v;
        if (out16) out16[(size_t)m * N + n] = f2bf(v);
      }
    }
  }
}

// ---------------------------------------------------------------------------
// Fused GEMM + residual + LayerNorm. out[M,256] = LN(A16@Wt^T + bias + res).
// BM=128, BN=256 (full row per block), BK=64, 4 waves each owning 32 rows.
// acc[2][16] f32x4 per thread; row stats via 16-lane shfl_xor (1,2,4,8).
// ---------------------------------------------------------------------------
__global__ __launch_bounds__(256, 2) void gemm_ln_k(
    const unsigned short* __restrict__ A, const unsigned short* __restrict__ Wt,
    const float* __restrict__ bias, const float* __restrict__ res,
    const float* __restrict__ g, const float* __restrict__ b,
    float* __restrict__ outf, unsigned short* __restrict__ out16)
{
  __shared__ unsigned short As[128 * 64];   // 16 KB
  __shared__ unsigned short Bs[256 * 64];   // 32 KB
  const int t = threadIdx.x;
  const int lane = t & 63, wave = t >> 6;
  const int m0 = blockIdx.x * 128;

  const int lrow = lane >> 3;
  const int pcol = (lane & 7) << 4;
  const int scol = pcol ^ (lrow << 4);

  f32x4v acc[2][16];
#pragma unroll
  for (int i = 0; i < 2; ++i)
#pragma unroll
    for (int j = 0; j < 16; ++j) acc[i][j] = (f32x4v){0.f, 0.f, 0.f, 0.f};

  const int fr = lane & 15;
  const int fq = lane >> 4;
  const int fkb = fq << 4;

  for (int k0 = 0; k0 < 256; k0 += 64) {
#pragma unroll
    for (int i = 0; i < 4; ++i) {
      const int row = wave * 32 + i * 8 + lrow;
      const unsigned short* gp = A + (size_t)(m0 + row) * 256 + k0 + (scol >> 1);
      unsigned short* s = As + (wave * 32 + i * 8) * 64;
      __builtin_amdgcn_global_load_lds(
          (const __attribute__((address_space(1))) void*)gp,
          (__attribute__((address_space(3))) void*)s, 16, 0, 0);
    }
#pragma unroll
    for (int i = 0; i < 8; ++i) {
      const int row = wave * 64 + i * 8 + lrow;  // n index 0..255
      const unsigned short* gp = Wt + (size_t)row * 256 + k0 + (scol >> 1);
      unsigned short* s = Bs + (wave * 64 + i * 8) * 64;
      __builtin_amdgcn_global_load_lds(
          (const __attribute__((address_space(1))) void*)gp,
          (__attribute__((address_space(3))) void*)s, 16, 0, 0);
    }
    __syncthreads();

    bf16x8 af[2][2];
#pragma unroll
    for (int i = 0; i < 2; ++i) {
      const int row = wave * 32 + i * 16 + fr;
      const char* base = (const char*)As + row * 128;
#pragma unroll
      for (int kk = 0; kk < 2; ++kk) {
        const int colb = (kk * 64 + fkb) ^ ((row & 7) << 4);
        af[i][kk] = *(const bf16x8*)(base + colb);
      }
    }
#pragma unroll
    for (int j = 0; j < 16; ++j) {
      const int row = j * 16 + fr;
      const char* base = (const char*)Bs + row * 128;
      bf16x8 b0, b1;
      {
        const int colb0 = (0 + fkb) ^ ((row & 7) << 4);
        const int colb1 = (64 + fkb) ^ ((row & 7) << 4);
        b0 = *(const bf16x8*)(base + colb0);
        b1 = *(const bf16x8*)(base + colb1);
      }
#pragma unroll
      for (int i = 0; i < 2; ++i) {
        acc[i][j] = __builtin_amdgcn_mfma_f32_16x16x32_bf16(af[i][0], b0, acc[i][j], 0, 0, 0);
        acc[i][j] = __builtin_amdgcn_mfma_f32_16x16x32_bf16(af[i][1], b1, acc[i][j], 0, 0, 0);
      }
    }
    __syncthreads();
  }

  // ---- epilogue: + bias + res, then per-row LayerNorm ----
  float biasj[16], gj[16], bjv[16];
#pragma unroll
  for (int j = 0; j < 16; ++j) {
    const int n = j * 16 + fr;
    biasj[j] = bias[n]; gj[j] = g[n]; bjv[j] = b[n];
  }

#pragma unroll
  for (int i = 0; i < 2; ++i) {
    const int mrow0 = m0 + wave * 32 + i * 16 + fq * 4;
#pragma unroll
    for (int r = 0; r < 4; ++r) {
      const size_t rowoff = (size_t)(mrow0 + r) * 256;
      float s = 0.f;
#pragma unroll
      for (int j = 0; j < 16; ++j) {
        float v = acc[i][j][r] + biasj[j] + res[rowoff + j * 16 + fr];
        acc[i][j][r] = v;
        s += v;
      }
#pragma unroll
      for (int o = 1; o < 16; o <<= 1) s += __shfl_xor(s, o);
      const float mean = s * (1.f / 256.f);
      float ss = 0.f;
#pragma unroll
      for (int j = 0; j < 16; ++j) {
        const float d = acc[i][j][r] - mean;
        ss += d * d;
      }
#pragma unroll
      for (int o = 1; o < 16; o <<= 1) ss += __shfl_xor(ss, o);
      const float rstd = rsqrtf(ss * (1.f / 256.f) + 1e-5f);
#pragma unroll
      for (int j = 0; j < 16; ++j) {
        const float v = (acc[i][j][r] - mean) * rstd * gj[j] + bjv[j];
        if (outf)  outf[rowoff + j * 16 + fr] = v;
        if (out16) out16[rowoff + j * 16 + fr] = f2bf(v);
      }
    }
  }
}

// ---------------------------------------------------------------------------
// Deformable sampling: 8 tokens/block, bf16 value, fused softmax.
// LDS: skewed slots [ti][e + (e>>4)], weights half4 (8B) + indices short4 (8B)
// -> 17.4 KB/block -> 8 blocks/CU.
// ---------------------------------------------------------------------------
__global__ __launch_bounds__(256) void samp_k(
    const unsigned short* __restrict__ value16, const float* __restrict__ fused,
    const float* __restrict__ ref, unsigned short* __restrict__ att16)
{
  const int tok0 = blockIdx.x * 8;
  __shared__ half4v  swv[8][136];
  __shared__ short4v siv[8][136];
  const int t = threadIdx.x;

#pragma unroll
  for (int it = 0; it < 4; ++it) {
    const int idx = it * 256 + t;
    const int ti = idx >> 7;
    const int e  = idx & 127;              // h*16 + lvl*4 + p
    const int tok = tok0 + ti;
    const int h = e >> 4;
    const int lvl = (e >> 2) & 3;
    const int HW[4] = {64, 32, 16, 8};
    const int LS[4] = {0, 4096, 5120, 5376};
    const int Wl = HW[lvl];

    const float lg = fused[(size_t)tok * 384 + 256 + e];
    float mx = lg;
#pragma unroll
    for (int o = 1; o < 16; o <<= 1) mx = fmaxf(mx, __shfl_xor(mx, o, 16));
    const float ex = __expf(lg - mx);
    float sm = ex;
#pragma unroll
    for (int o = 1; o < 16; o <<= 1) sm += __shfl_xor(sm, o, 16);
    const float a = ex / sm;

    const float ox = fused[(size_t)tok * 384 + e * 2 + 0];
    const float oy = fused[(size_t)tok * 384 + e * 2 + 1];
    const float rx = ref[(size_t)tok * 8 + lvl * 2 + 0];
    const float ry = ref[(size_t)tok * 8 + lvl * 2 + 1];
    const float x = rx * (float)Wl + ox - 0.5f;
    const float y = ry * (float)Wl + oy - 0.5f;
    const float x0f = floorf(x), y0f = floorf(y);
    const float fx = x - x0f, fy = y - y0f;
    const int x0 = (int)x0f, y0 = (int)y0f;

    const int xi1 = x0 + 1, yi1 = y0 + 1;
    const float wx0 = 1.f - fx, wx1 = fx, wy0 = 1.f - fy, wy1 = fy;
    const int xc0 = min(max(x0, 0), Wl - 1), xc1 = min(max(xi1, 0), Wl - 1);
    const int yc0 = min(max(y0, 0), Wl - 1), yc1 = min(max(yi1, 0), Wl - 1);
    const bool vx0 = (x0 >= 0) & (x0 < Wl), vx1 = (xi1 >= 0) & (xi1 < Wl);
    const bool vy0 = (y0 >= 0) & (y0 < Wl), vy1 = (yi1 >= 0) & (yi1 < Wl);
    half4v hw;
    hw.x = (_Float16)((vx0 & vy0) ? a * wx0 * wy0 : 0.f);
    hw.y = (_Float16)((vx1 & vy0) ? a * wx1 * wy0 : 0.f);
    hw.z = (_Float16)((vx0 & vy1) ? a * wx0 * wy1 : 0.f);
    hw.w = (_Float16)((vx1 & vy1) ? a * wx1 * wy1 : 0.f);
    short4v hs;
    hs.x = (short)(LS[lvl] + yc0 * Wl + xc0);
    hs.y = (short)(LS[lvl] + yc0 * Wl + xc1);
    hs.z = (short)(LS[lvl] + yc1 * Wl + xc0);
    hs.w = (short)(LS[lvl] + yc1 * Wl + xc1);
    const int sl = e + h;
    swv[ti][sl] = hw;
    siv[ti][sl] = hs;
  }
  __syncthreads();

  const int wave = t >> 6, lane = t & 63;
  const int ti = wave * 2 + (lane >> 5);
  const int h = (lane >> 2) & 7, dg = lane & 3;
  const int tok = tok0 + ti;
  const int vbase = (tok / LQ_) * LQ_;
  const unsigned short* vb = value16 + (size_t)vbase * 256 + h * 32 + dg * 8;
  float acc[8] = {0.f, 0.f, 0.f, 0.f, 0.f, 0.f, 0.f, 0.f};
  const int ebase = h * 17;

#pragma unroll 4
  for (int p = 0; p < 16; ++p) {
    const half4v hw = swv[ti][ebase + p];
    const short4v hs = siv[ti][ebase + p];
    const float w0 = (float)hw.x, w1 = (float)hw.y, w2 = (float)hw.z, w3 = (float)hw.w;
    const uint4 u0 = *(const uint4*)(vb + (size_t)(int)hs.x * 256);
    const uint4 u1 = *(const uint4*)(vb + (size_t)(int)hs.y * 256);
    const uint4 u2 = *(const uint4*)(vb + (size_t)(int)hs.z * 256);
    const uint4 u3 = *(const uint4*)(vb + (size_t)(int)hs.w * 256);
#define ACC4(U, W)                                            \
    acc[0] = fmaf(W, bflo(U.x), acc[0]);                      \
    acc[1] = fmaf(W, bfhi(U.x), acc[1]);                      \
    acc[2] = fmaf(W, bflo(U.y), acc[2]);                      \
    acc[3] = fmaf(W, bfhi(U.y), acc[3]);                      \
    acc[4] = fmaf(W, bflo(U.z), acc[4]);                      \
    acc[5] = fmaf(W, bfhi(U.z), acc[5]);                      \
    acc[6] = fmaf(W, bflo(U.w), acc[6]);                      \
    acc[7] = fmaf(W, bfhi(U.w), acc[7]);
    ACC4(u0, w0) ACC4(u1, w1) ACC4(u2, w2) ACC4(u3, w3)
#undef ACC4
  }

  uint4 o;
  o.x = (unsigned)f2bf(acc[0]) | ((unsigned)f2bf(acc[1]) << 16);
  o.y = (unsigned)f2bf(acc[2]) | ((unsigned)f2bf(acc[3]) << 16);
  o.z = (unsigned)f2bf(acc[4]) | ((unsigned)f2bf(acc[5]) << 16);
  o.w = (unsigned)f2bf(acc[6]) | ((unsigned)f2bf(acc[7]) << 16);
  *(uint4*)(att16 + (size_t)tok * 256 + h * 32 + dg * 8) = o;
}

// ---------------------------------------------------------------------------
extern "C" void kernel_launch(void* const* d_in, const int* in_sizes, int n_in,
                              void* d_out, int out_size, void* d_ws, size_t ws_size,
                              hipStream_t stream)
{
  const float* src   = (const float*)d_in[0];
  const float* pos   = (const float*)d_in[1];
  const float* ref   = (const float*)d_in[2];
  const float* Wv    = (const float*)d_in[5];
  const float* bv    = (const float*)d_in[6];
  const float* Woff  = (const float*)d_in[7];
  const float* boff  = (const float*)d_in[8];
  const float* Wattn = (const float*)d_in[9];
  const float* battn = (const float*)d_in[10];
  const float* Wout  = (const float*)d_in[11];
  const float* bout  = (const float*)d_in[12];
  const float* g1    = (const float*)d_in[13];
  const float* b1    = (const float*)d_in[14];
  const float* W1    = (const float*)d_in[15];
  const float* bb1   = (const float*)d_in[16];
  const float* W2    = (const float*)d_in[17];
  const float* bb2   = (const float*)d_in[18];
  const float* g3    = (const float*)d_in[19];
  const float* b3    = (const float*)d_in[20];

  float* out = (float*)d_out;
  char* ws = (char*)d_ws;
  const size_t M = M_TOK;

  float* bufA = (float*)ws;                              // f32 M*256: value16 alias -> sxy f32
  float* bufB = (float*)(ws + M * 256 * 4);              // f32 M*384: fused off|attn
  unsigned short* bufE = (unsigned short*)(ws + M * 256 * 4 + M * 384 * 4);  // s16 -> att16 -> h16
  unsigned short* bufF = bufE + M * 256;                 // q16 -> sxy16
  unsigned short* bufG = bufF + M * 256;                 // bf16 weights
  unsigned short* value16 = (unsigned short*)bufA;

  unsigned short* WvT     = bufG + 0;
  unsigned short* WfusedT = bufG + 65536;
  unsigned short* WoutT   = bufG + 163840;
  unsigned short* W1T     = bufG + 229376;
  unsigned short* W2T     = bufG + 294912;

  const dim3 blk(256);

  prep_x<<<dim3(5440), blk, 0, stream>>>(src, pos, bufE, bufF);
  prep_w<<<dim3(1408), blk, 0, stream>>>(Wv, Woff, Wattn, Wout, W1, W2, bufG);

  // value16 = bf16(src @ Wv + bv)
  gemm_bf16_k<<<dim3(170, 2), blk, 0, stream>>>(bufE, WvT, bv, nullptr, nullptr, value16, 256, 0);
  // fused = q @ [Woff|Wattn] + [boff|battn]
  gemm_bf16_k<<<dim3(170, 3), blk, 0, stream>>>(bufF, WfusedT, boff, battn, bufB, nullptr, 384, 0);
  // sampling (with in-kernel softmax) -> att16
  samp_k<<<dim3(2720), blk, 0, stream>>>(value16, bufB, ref, bufE);
  // sxy = LN(att @ Wout + bout + src) -> bufA f32 + bufF bf16   [value16 lifetime ends here]
  gemm_ln_k<<<dim3(170), blk, 0, stream>>>(bufE, WoutT, bout, src, g1, b1, bufA, bufF);
  // h16 = bf16(relu(sxy @ W1 + bb1))
  gemm_bf16_k<<<dim3(170, 2), blk, 0, stream>>>(bufF, W1T, bb1, nullptr, nullptr, bufE, 256, 1);
  // out = LN(h @ W2 + bb2 + sxy)
  gemm_ln_k<<<dim3(170), blk, 0, stream>>>(bufE, W2T, bb2, bufA, g3, b3, out, nullptr);
}

// Round 5
// 123.243 us; speedup vs baseline: 3.9117x; 1.1698x over previous
//
#include <hip/hip_runtime.h>
#include <cstddef>
#include <cstdint>

#define M_TOK 21760
#define LQ_ 5440

typedef __bf16 bf16x8 __attribute__((ext_vector_type(8)));
typedef float f32x4v __attribute__((ext_vector_type(4)));
typedef _Float16 half4v __attribute__((ext_vector_type(4)));
typedef short short4v __attribute__((ext_vector_type(4)));

__device__ __forceinline__ unsigned short f2bf(float f) {
  unsigned u = __builtin_bit_cast(unsigned, f);
  unsigned r = u + 0x7fffu + ((u >> 16) & 1u);
  return (unsigned short)(r >> 16);
}
__device__ __forceinline__ float bflo(unsigned u) {
  return __builtin_bit_cast(float, u << 16);
}
__device__ __forceinline__ float bfhi(unsigned u) {
  return __builtin_bit_cast(float, u & 0xffff0000u);
}

// ---------------------------------------------------------------------------
// prep_x: s16 = bf16(src), q16 = bf16(src+pos)
// ---------------------------------------------------------------------------
__global__ __launch_bounds__(256) void prep_x(
    const float* __restrict__ src, const float* __restrict__ pos,
    unsigned short* __restrict__ s16, unsigned short* __restrict__ q16)
{
  const int i = blockIdx.x * 256 + threadIdx.x;
  const float4 s = ((const float4*)src)[i];
  const float4 p = ((const float4*)pos)[i];
  ushort4 a, b;
  a.x = f2bf(s.x); a.y = f2bf(s.y); a.z = f2bf(s.z); a.w = f2bf(s.w);
  b.x = f2bf(s.x + p.x); b.y = f2bf(s.y + p.y); b.z = f2bf(s.z + p.z); b.w = f2bf(s.w + p.w);
  ((ushort4*)s16)[i] = a;
  ((ushort4*)q16)[i] = b;
}

// ---------------------------------------------------------------------------
// prep_w: cast + transpose weights into Wt[n][k] bf16, packed.
// ---------------------------------------------------------------------------
__global__ __launch_bounds__(256) void prep_w(
    const float* __restrict__ Wv, const float* __restrict__ Woff,
    const float* __restrict__ Wattn, const float* __restrict__ Wout,
    const float* __restrict__ W1, const float* __restrict__ W2,
    unsigned short* __restrict__ G)
{
  const int gid = blockIdx.x * 256 + threadIdx.x;
  const float* srcs[6] = {Wv, Woff, Wattn, Wout, W1, W2};
  const int starts[7] = {0, 65536, 131072, 163840, 229376, 294912, 360448};
  const int Nn[6] = {256, 256, 128, 256, 256, 256};
  int m = 0;
#pragma unroll
  for (int i = 1; i < 6; ++i) m += (gid >= starts[i]);
  const int local = gid - starts[m];
  const int n = local >> 8;
  const int k = local & 255;
  G[gid] = f2bf(srcs[m][(size_t)k * Nn[m] + n]);
}

// ---------------------------------------------------------------------------
// bf16 MFMA GEMM (no LN): out[M,N] = A16 @ Wt^T. 128x128 tile, BK=64.
// ---------------------------------------------------------------------------
__global__ __launch_bounds__(256, 2) void gemm_bf16_k(
    const unsigned short* __restrict__ A, const unsigned short* __restrict__ Wt,
    const float* __restrict__ bias, const float* __restrict__ bias2,
    float* __restrict__ outf, unsigned short* __restrict__ out16,
    int N, int relu)
{
  __shared__ unsigned short As[128 * 64];
  __shared__ unsigned short Bs[128 * 64];
  const int t = threadIdx.x;
  const int lane = t & 63, wave = t >> 6;
  const int wm = wave >> 1, wn = wave & 1;
  const int m0 = blockIdx.x * 128, n0 = blockIdx.y * 128;

  const int lrow = lane >> 3;
  const int pcol = (lane & 7) << 4;
  const int scol = pcol ^ (lrow << 4);

  f32x4v acc[4][4];
#pragma unroll
  for (int i = 0; i < 4; ++i)
#pragma unroll
    for (int j = 0; j < 4; ++j) acc[i][j] = (f32x4v){0.f, 0.f, 0.f, 0.f};

  const int fr = lane & 15;
  const int fkb = (lane >> 4) << 4;

  for (int k0 = 0; k0 < 256; k0 += 64) {
#pragma unroll
    for (int i = 0; i < 4; ++i) {
      const int row = wave * 32 + i * 8 + lrow;
      const unsigned short* g = A + (size_t)(m0 + row) * 256 + k0 + (scol >> 1);
      unsigned short* s = As + (wave * 32 + i * 8) * 64;
      __builtin_amdgcn_global_load_lds(
          (const __attribute__((address_space(1))) void*)g,
          (__attribute__((address_space(3))) void*)s, 16, 0, 0);
    }
#pragma unroll
    for (int i = 0; i < 4; ++i) {
      const int row = wave * 32 + i * 8 + lrow;
      const unsigned short* g = Wt + (size_t)(n0 + row) * 256 + k0 + (scol >> 1);
      unsigned short* s = Bs + (wave * 32 + i * 8) * 64;
      __builtin_amdgcn_global_load_lds(
          (const __attribute__((address_space(1))) void*)g,
          (__attribute__((address_space(3))) void*)s, 16, 0, 0);
    }
    __syncthreads();

    bf16x8 af[4][2], bfr[4][2];
#pragma unroll
    for (int i = 0; i < 4; ++i) {
      const int row = wm * 64 + i * 16 + fr;
      const char* base = (const char*)As + row * 128;
#pragma unroll
      for (int kk = 0; kk < 2; ++kk) {
        const int colb = (kk * 64 + fkb) ^ ((row & 7) << 4);
        af[i][kk] = *(const bf16x8*)(base + colb);
      }
    }
#pragma unroll
    for (int j = 0; j < 4; ++j) {
      const int row = wn * 64 + j * 16 + fr;
      const char* base = (const char*)Bs + row * 128;
#pragma unroll
      for (int kk = 0; kk < 2; ++kk) {
        const int colb = (kk * 64 + fkb) ^ ((row & 7) << 4);
        bfr[j][kk] = *(const bf16x8*)(base + colb);
      }
    }
#pragma unroll
    for (int i = 0; i < 4; ++i)
#pragma unroll
      for (int j = 0; j < 4; ++j) {
        acc[i][j] = __builtin_amdgcn_mfma_f32_16x16x32_bf16(af[i][0], bfr[j][0], acc[i][j], 0, 0, 0);
        acc[i][j] = __builtin_amdgcn_mfma_f32_16x16x32_bf16(af[i][1], bfr[j][1], acc[i][j], 0, 0, 0);
      }
    __syncthreads();
  }

  const float* bsel = bias;
  int nsub = 0;
  if (bias2 && n0 >= 256) { bsel = bias2; nsub = 256; }

  const int fq = lane >> 4;
#pragma unroll
  for (int j = 0; j < 4; ++j) {
    const int n = n0 + wn * 64 + j * 16 + fr;
    const float bj = bsel[n - nsub];
#pragma unroll
    for (int i = 0; i < 4; ++i) {
#pragma unroll
      for (int r = 0; r < 4; ++r) {
        const int m = m0 + wm * 64 + i * 16 + fq * 4 + r;
        float v = acc[i][j][r] + bj;
        if (relu) v = fmaxf(v, 0.f);
        if (outf) outf[(size_t)m * N + n] = v;
        if (out16) out16[(size_t)m * N + n] = f2bf(v);
      }
    }
  }
}

// ---------------------------------------------------------------------------
// Fused GEMM + residual + LayerNorm, v2 (occupancy-fixed).
// out[M,256] = LN(A16@Wt^T + bias + res).
// BM=32, BN=256, BK=64. 512 threads = 8 waves; wave w: rows (w&1)*16..+15,
// cols (w>>1)*64..+63 -> acc[4] f32x4. Grid = M/32 = 680.
// LDS: As 4KB + Bs 32.5KB; Bs reused as f32 Cs[32][260] for the LN epilogue.
// ---------------------------------------------------------------------------
__global__ __launch_bounds__(512, 4) void gemm_ln_k(
    const unsigned short* __restrict__ A, const unsigned short* __restrict__ Wt,
    const float* __restrict__ bias, const float* __restrict__ res,
    const float* __restrict__ g, const float* __restrict__ b,
    float* __restrict__ outf, unsigned short* __restrict__ out16)
{
  __shared__ unsigned short As[32 * 64];          // 4 KB
  __shared__ unsigned short Bs[256 * 64 + 288];   // 32.5 KB; epilogue: f32 [32][260]
  const int t = threadIdx.x;
  const int lane = t & 63, wave = t >> 6;         // 8 waves
  const int rt = wave & 1, cg = wave >> 1;        // row-tile, col-group
  const int m0 = blockIdx.x * 32;

  const int lrow = lane >> 3;
  const int pcol = (lane & 7) << 4;
  const int scol = pcol ^ (lrow << 4);

  f32x4v acc[4];
#pragma unroll
  for (int j = 0; j < 4; ++j) acc[j] = (f32x4v){0.f, 0.f, 0.f, 0.f};

  const int fr = lane & 15;
  const int fq = lane >> 4;
  const int fkb = fq << 4;

  for (int k0 = 0; k0 < 256; k0 += 64) {
    if (wave < 4) {                       // A tile: 32 rows x 64 k
      const int row = wave * 8 + lrow;
      const unsigned short* gp = A + (size_t)(m0 + row) * 256 + k0 + (scol >> 1);
      unsigned short* s = As + (wave * 8) * 64;
      __builtin_amdgcn_global_load_lds(
          (const __attribute__((address_space(1))) void*)gp,
          (__attribute__((address_space(3))) void*)s, 16, 0, 0);
    }
#pragma unroll
    for (int i = 0; i < 4; ++i) {         // B tile: 256 rows x 64 k
      const int row = wave * 32 + i * 8 + lrow;
      const unsigned short* gp = Wt + (size_t)row * 256 + k0 + (scol >> 1);
      unsigned short* s = Bs + (wave * 32 + i * 8) * 64;
      __builtin_amdgcn_global_load_lds(
          (const __attribute__((address_space(1))) void*)gp,
          (__attribute__((address_space(3))) void*)s, 16, 0, 0);
    }
    __syncthreads();

    bf16x8 af0, af1;
    {
      const int arow = rt * 16 + fr;
      const char* abase = (const char*)As + arow * 128;
      af0 = *(const bf16x8*)(abase + ((0 + fkb) ^ ((arow & 7) << 4)));
      af1 = *(const bf16x8*)(abase + ((64 + fkb) ^ ((arow & 7) << 4)));
    }
#pragma unroll
    for (int j = 0; j < 4; ++j) {
      const int brow = cg * 64 + j * 16 + fr;
      const char* bbase = (const char*)Bs + brow * 128;
      const bf16x8 b0 = *(const bf16x8*)(bbase + ((0 + fkb) ^ ((brow & 7) << 4)));
      const bf16x8 b1 = *(const bf16x8*)(bbase + ((64 + fkb) ^ ((brow & 7) << 4)));
      acc[j] = __builtin_amdgcn_mfma_f32_16x16x32_bf16(af0, b0, acc[j], 0, 0, 0);
      acc[j] = __builtin_amdgcn_mfma_f32_16x16x32_bf16(af1, b1, acc[j], 0, 0, 0);
    }
    __syncthreads();
  }

  // ---- dump acc to LDS as f32 [32][260] (reusing Bs) ----
  float* Cs = (float*)Bs;
#pragma unroll
  for (int j = 0; j < 4; ++j) {
    const int col = cg * 64 + j * 16 + fr;
#pragma unroll
    for (int rr = 0; rr < 4; ++rr) {
      const int row = rt * 16 + fq * 4 + rr;
      Cs[row * 260 + col] = acc[j][rr];
    }
  }
  __syncthreads();

  // ---- LN: wave handles 4 rows; 16 lanes per row ----
  const int lg = lane >> 4, li = lane & 15;
  const int row = wave * 4 + lg;
  const size_t rowoff = (size_t)(m0 + row) * 256;

  float4 v[4];
  float s = 0.f;
#pragma unroll
  for (int c4 = 0; c4 < 4; ++c4) {
    const int col = c4 * 64 + li * 4;
    float4 x = *(float4*)&Cs[row * 260 + col];
    const float4 bi = *(const float4*)&bias[col];
    const float4 rv = *(const float4*)&res[rowoff + col];
    x.x += bi.x + rv.x; x.y += bi.y + rv.y;
    x.z += bi.z + rv.z; x.w += bi.w + rv.w;
    v[c4] = x;
    s += x.x + x.y + x.z + x.w;
  }
#pragma unroll
  for (int o = 1; o < 16; o <<= 1) s += __shfl_xor(s, o);
  const float mean = s * (1.f / 256.f);
  float ss = 0.f;
#pragma unroll
  for (int c4 = 0; c4 < 4; ++c4) {
    const float d0 = v[c4].x - mean, d1 = v[c4].y - mean;
    const float d2 = v[c4].z - mean, d3 = v[c4].w - mean;
    ss += d0 * d0 + d1 * d1 + d2 * d2 + d3 * d3;
  }
#pragma unroll
  for (int o = 1; o < 16; o <<= 1) ss += __shfl_xor(ss, o);
  const float rstd = rsqrtf(ss * (1.f / 256.f) + 1e-5f);

#pragma unroll
  for (int c4 = 0; c4 < 4; ++c4) {
    const int col = c4 * 64 + li * 4;
    const float4 gv = *(const float4*)&g[col];
    const float4 bv = *(const float4*)&b[col];
    float4 o4;
    o4.x = (v[c4].x - mean) * rstd * gv.x + bv.x;
    o4.y = (v[c4].y - mean) * rstd * gv.y + bv.y;
    o4.z = (v[c4].z - mean) * rstd * gv.z + bv.z;
    o4.w = (v[c4].w - mean) * rstd * gv.w + bv.w;
    if (outf) *(float4*)(outf + rowoff + col) = o4;
    if (out16) {
      ushort4 o;
      o.x = f2bf(o4.x); o.y = f2bf(o4.y); o.z = f2bf(o4.z); o.w = f2bf(o4.w);
      *(ushort4*)(out16 + rowoff + col) = o;
    }
  }
}

// ---------------------------------------------------------------------------
// Deformable sampling: 8 tokens/block, bf16 value, fused softmax.
// ---------------------------------------------------------------------------
__global__ __launch_bounds__(256) void samp_k(
    const unsigned short* __restrict__ value16, const float* __restrict__ fused,
    const float* __restrict__ ref, unsigned short* __restrict__ att16)
{
  const int tok0 = blockIdx.x * 8;
  __shared__ half4v  swv[8][136];
  __shared__ short4v siv[8][136];
  const int t = threadIdx.x;

#pragma unroll
  for (int it = 0; it < 4; ++it) {
    const int idx = it * 256 + t;
    const int ti = idx >> 7;
    const int e  = idx & 127;              // h*16 + lvl*4 + p
    const int tok = tok0 + ti;
    const int h = e >> 4;
    const int lvl = (e >> 2) & 3;
    const int HW[4] = {64, 32, 16, 8};
    const int LS[4] = {0, 4096, 5120, 5376};
    const int Wl = HW[lvl];

    const float lg = fused[(size_t)tok * 384 + 256 + e];
    float mx = lg;
#pragma unroll
    for (int o = 1; o < 16; o <<= 1) mx = fmaxf(mx, __shfl_xor(mx, o, 16));
    const float ex = __expf(lg - mx);
    float sm = ex;
#pragma unroll
    for (int o = 1; o < 16; o <<= 1) sm += __shfl_xor(sm, o, 16);
    const float a = ex / sm;

    const float ox = fused[(size_t)tok * 384 + e * 2 + 0];
    const float oy = fused[(size_t)tok * 384 + e * 2 + 1];
    const float rx = ref[(size_t)tok * 8 + lvl * 2 + 0];
    const float ry = ref[(size_t)tok * 8 + lvl * 2 + 1];
    const float x = rx * (float)Wl + ox - 0.5f;
    const float y = ry * (float)Wl + oy - 0.5f;
    const float x0f = floorf(x), y0f = floorf(y);
    const float fx = x - x0f, fy = y - y0f;
    const int x0 = (int)x0f, y0 = (int)y0f;

    const int xi1 = x0 + 1, yi1 = y0 + 1;
    const float wx0 = 1.f - fx, wx1 = fx, wy0 = 1.f - fy, wy1 = fy;
    const int xc0 = min(max(x0, 0), Wl - 1), xc1 = min(max(xi1, 0), Wl - 1);
    const int yc0 = min(max(y0, 0), Wl - 1), yc1 = min(max(yi1, 0), Wl - 1);
    const bool vx0 = (x0 >= 0) & (x0 < Wl), vx1 = (xi1 >= 0) & (xi1 < Wl);
    const bool vy0 = (y0 >= 0) & (y0 < Wl), vy1 = (yi1 >= 0) & (yi1 < Wl);
    half4v hw;
    hw.x = (_Float16)((vx0 & vy0) ? a * wx0 * wy0 : 0.f);
    hw.y = (_Float16)((vx1 & vy0) ? a * wx1 * wy0 : 0.f);
    hw.z = (_Float16)((vx0 & vy1) ? a * wx0 * wy1 : 0.f);
    hw.w = (_Float16)((vx1 & vy1) ? a * wx1 * wy1 : 0.f);
    short4v hs;
    hs.x = (short)(LS[lvl] + yc0 * Wl + xc0);
    hs.y = (short)(LS[lvl] + yc0 * Wl + xc1);
    hs.z = (short)(LS[lvl] + yc1 * Wl + xc0);
    hs.w = (short)(LS[lvl] + yc1 * Wl + xc1);
    const int sl = e + h;
    swv[ti][sl] = hw;
    siv[ti][sl] = hs;
  }
  __syncthreads();

  const int wave = t >> 6, lane = t & 63;
  const int ti = wave * 2 + (lane >> 5);
  const int h = (lane >> 2) & 7, dg = lane & 3;
  const int tok = tok0 + ti;
  const int vbase = (tok / LQ_) * LQ_;
  const unsigned short* vb = value16 + (size_t)vbase * 256 + h * 32 + dg * 8;
  float acc[8] = {0.f, 0.f, 0.f, 0.f, 0.f, 0.f, 0.f, 0.f};
  const int ebase = h * 17;

#pragma unroll 4
  for (int p = 0; p < 16; ++p) {
    const half4v hw = swv[ti][ebase + p];
    const short4v hs = siv[ti][ebase + p];
    const float w0 = (float)hw.x, w1 = (float)hw.y, w2 = (float)hw.z, w3 = (float)hw.w;
    const uint4 u0 = *(const uint4*)(vb + (size_t)(int)hs.x * 256);
    const uint4 u1 = *(const uint4*)(vb + (size_t)(int)hs.y * 256);
    const uint4 u2 = *(const uint4*)(vb + (size_t)(int)hs.z * 256);
    const uint4 u3 = *(const uint4*)(vb + (size_t)(int)hs.w * 256);
#define ACC4(U, W)                                            \
    acc[0] = fmaf(W, bflo(U.x), acc[0]);                      \
    acc[1] = fmaf(W, bfhi(U.x), acc[1]);                      \
    acc[2] = fmaf(W, bflo(U.y), acc[2]);                      \
    acc[3] = fmaf(W, bfhi(U.y), acc[3]);                      \
    acc[4] = fmaf(W, bflo(U.z), acc[4]);                      \
    acc[5] = fmaf(W, bfhi(U.z), acc[5]);                      \
    acc[6] = fmaf(W, bflo(U.w), acc[6]);                      \
    acc[7] = fmaf(W, bfhi(U.w), acc[7]);
    ACC4(u0, w0) ACC4(u1, w1) ACC4(u2, w2) ACC4(u3, w3)
#undef ACC4
  }

  uint4 o;
  o.x = (unsigned)f2bf(acc[0]) | ((unsigned)f2bf(acc[1]) << 16);
  o.y = (unsigned)f2bf(acc[2]) | ((unsigned)f2bf(acc[3]) << 16);
  o.z = (unsigned)f2bf(acc[4]) | ((unsigned)f2bf(acc[5]) << 16);
  o.w = (unsigned)f2bf(acc[6]) | ((unsigned)f2bf(acc[7]) << 16);
  *(uint4*)(att16 + (size_t)tok * 256 + h * 32 + dg * 8) = o;
}

// ---------------------------------------------------------------------------
extern "C" void kernel_launch(void* const* d_in, const int* in_sizes, int n_in,
                              void* d_out, int out_size, void* d_ws, size_t ws_size,
                              hipStream_t stream)
{
  const float* src   = (const float*)d_in[0];
  const float* pos   = (const float*)d_in[1];
  const float* ref   = (const float*)d_in[2];
  const float* Wv    = (const float*)d_in[5];
  const float* bv    = (const float*)d_in[6];
  const float* Woff  = (const float*)d_in[7];
  const float* boff  = (const float*)d_in[8];
  const float* Wattn = (const float*)d_in[9];
  const float* battn = (const float*)d_in[10];
  const float* Wout  = (const float*)d_in[11];
  const float* bout  = (const float*)d_in[12];
  const float* g1    = (const float*)d_in[13];
  const float* b1    = (const float*)d_in[14];
  const float* W1    = (const float*)d_in[15];
  const float* bb1   = (const float*)d_in[16];
  const float* W2    = (const float*)d_in[17];
  const float* bb2   = (const float*)d_in[18];
  const float* g3    = (const float*)d_in[19];
  const float* b3    = (const float*)d_in[20];

  float* out = (float*)d_out;
  char* ws = (char*)d_ws;
  const size_t M = M_TOK;

  float* bufA = (float*)ws;                              // f32 M*256: value16 alias -> sxy f32
  float* bufB = (float*)(ws + M * 256 * 4);              // f32 M*384: fused off|attn
  unsigned short* bufE = (unsigned short*)(ws + M * 256 * 4 + M * 384 * 4);  // s16 -> att16 -> h16
  unsigned short* bufF = bufE + M * 256;                 // q16 -> sxy16
  unsigned short* bufG = bufF + M * 256;                 // bf16 weights
  unsigned short* value16 = (unsigned short*)bufA;

  unsigned short* WvT     = bufG + 0;
  unsigned short* WfusedT = bufG + 65536;
  unsigned short* WoutT   = bufG + 163840;
  unsigned short* W1T     = bufG + 229376;
  unsigned short* W2T     = bufG + 294912;

  const dim3 blk(256);

  prep_x<<<dim3(5440), blk, 0, stream>>>(src, pos, bufE, bufF);
  prep_w<<<dim3(1408), blk, 0, stream>>>(Wv, Woff, Wattn, Wout, W1, W2, bufG);

  // value16 = bf16(src @ Wv + bv)
  gemm_bf16_k<<<dim3(170, 2), blk, 0, stream>>>(bufE, WvT, bv, nullptr, nullptr, value16, 256, 0);
  // fused = q @ [Woff|Wattn] + [boff|battn]
  gemm_bf16_k<<<dim3(170, 3), blk, 0, stream>>>(bufF, WfusedT, boff, battn, bufB, nullptr, 384, 0);
  // sampling (with in-kernel softmax) -> att16
  samp_k<<<dim3(2720), blk, 0, stream>>>(value16, bufB, ref, bufE);
  // sxy = LN(att @ Wout + bout + src) -> bufA f32 + bufF bf16
  gemm_ln_k<<<dim3(680), dim3(512), 0, stream>>>(bufE, WoutT, bout, src, g1, b1, bufA, bufF);
  // h16 = bf16(relu(sxy @ W1 + bb1))
  gemm_bf16_k<<<dim3(170, 2), blk, 0, stream>>>(bufF, W1T, bb1, nullptr, nullptr, bufE, 256, 1);
  // out = LN(h @ W2 + bb2 + sxy)
  gemm_ln_k<<<dim3(680), dim3(512), 0, stream>>>(bufE, W2T, bb2, bufA, g3, b3, out, nullptr);
}

// Round 6
// 116.991 us; speedup vs baseline: 4.1207x; 1.0534x over previous
//
#include <hip/hip_runtime.h>
#include <cstddef>
#include <cstdint>

#define M_TOK 21760
#define LQ_ 5440

typedef _Float16 f16x8 __attribute__((ext_vector_type(8)));
typedef _Float16 h2v __attribute__((ext_vector_type(2)));
typedef float f32x4v __attribute__((ext_vector_type(4)));
typedef _Float16 half4v __attribute__((ext_vector_type(4)));
typedef short short4v __attribute__((ext_vector_type(4)));

__device__ __forceinline__ unsigned short f2h(float f) {
  return __builtin_bit_cast(unsigned short, (_Float16)f);
}
__device__ __forceinline__ unsigned pack2h(float a, float b) {
  h2v p; p[0] = (_Float16)a; p[1] = (_Float16)b;
  return __builtin_bit_cast(unsigned, p);
}

// ---------------------------------------------------------------------------
// prep_x: s16 = f16(src), q16 = f16(src+pos)
// ---------------------------------------------------------------------------
__global__ __launch_bounds__(256) void prep_x(
    const float* __restrict__ src, const float* __restrict__ pos,
    unsigned short* __restrict__ s16, unsigned short* __restrict__ q16)
{
  const int i = blockIdx.x * 256 + threadIdx.x;
  const float4 s = ((const float4*)src)[i];
  const float4 p = ((const float4*)pos)[i];
  ushort4 a, b;
  a.x = f2h(s.x); a.y = f2h(s.y); a.z = f2h(s.z); a.w = f2h(s.w);
  b.x = f2h(s.x + p.x); b.y = f2h(s.y + p.y); b.z = f2h(s.z + p.z); b.w = f2h(s.w + p.w);
  ((ushort4*)s16)[i] = a;
  ((ushort4*)q16)[i] = b;
}

// ---------------------------------------------------------------------------
// prep_w: cast + transpose weights into Wt[n][k] f16, packed.
// ---------------------------------------------------------------------------
__global__ __launch_bounds__(256) void prep_w(
    const float* __restrict__ Wv, const float* __restrict__ Woff,
    const float* __restrict__ Wattn, const float* __restrict__ Wout,
    const float* __restrict__ W1, const float* __restrict__ W2,
    unsigned short* __restrict__ G)
{
  const int gid = blockIdx.x * 256 + threadIdx.x;
  const float* srcs[6] = {Wv, Woff, Wattn, Wout, W1, W2};
  const int starts[7] = {0, 65536, 131072, 163840, 229376, 294912, 360448};
  const int Nn[6] = {256, 256, 128, 256, 256, 256};
  int m = 0;
#pragma unroll
  for (int i = 1; i < 6; ++i) m += (gid >= starts[i]);
  const int local = gid - starts[m];
  const int n = local >> 8;
  const int k = local & 255;
  G[gid] = f2h(srcs[m][(size_t)k * Nn[m] + n]);
}

// ---------------------------------------------------------------------------
// Merged first-stage GEMM: grid (170, 5).
//  by<2 : value = s16 @ WvT  (N=256, cols by*128)     -> value16 (f16)
//  by>=2: fused = q16 @ WfT  (N=384, cols (by-2)*128) -> fused16 (f16)
// 128x128 tile, BK=64, 16x16x32 f16 MFMA, global_load_lds + XOR swizzle.
// ---------------------------------------------------------------------------
__global__ __launch_bounds__(256, 2) void gemm_qkv_k(
    const unsigned short* __restrict__ s16, const unsigned short* __restrict__ q16,
    const unsigned short* __restrict__ WvT, const unsigned short* __restrict__ WfT,
    const float* __restrict__ bv, const float* __restrict__ boff,
    const float* __restrict__ battn,
    unsigned short* __restrict__ value16, unsigned short* __restrict__ fused16)
{
  const int by = blockIdx.y;
  const bool isv = (by < 2);
  const unsigned short* A  = isv ? s16 : q16;
  const unsigned short* Wt = isv ? WvT : WfT;
  const int n0 = isv ? by * 128 : (by - 2) * 128;
  const int N  = isv ? 256 : 384;
  unsigned short* out16 = isv ? value16 : fused16;
  const float* bsel; int nsub;
  if (isv)            { bsel = bv;    nsub = 0; }
  else if (n0 < 256)  { bsel = boff;  nsub = 0; }
  else                { bsel = battn; nsub = 256; }

  __shared__ unsigned short As[128 * 64];
  __shared__ unsigned short Bs[128 * 64];
  const int t = threadIdx.x;
  const int lane = t & 63, wave = t >> 6;
  const int wm = wave >> 1, wn = wave & 1;
  const int m0 = blockIdx.x * 128;

  const int lrow = lane >> 3;
  const int pcol = (lane & 7) << 4;
  const int scol = pcol ^ (lrow << 4);

  f32x4v acc[4][4];
#pragma unroll
  for (int i = 0; i < 4; ++i)
#pragma unroll
    for (int j = 0; j < 4; ++j) acc[i][j] = (f32x4v){0.f, 0.f, 0.f, 0.f};

  const int fr = lane & 15;
  const int fkb = (lane >> 4) << 4;

  for (int k0 = 0; k0 < 256; k0 += 64) {
#pragma unroll
    for (int i = 0; i < 4; ++i) {
      const int row = wave * 32 + i * 8 + lrow;
      const unsigned short* g = A + (size_t)(m0 + row) * 256 + k0 + (scol >> 1);
      unsigned short* s = As + (wave * 32 + i * 8) * 64;
      __builtin_amdgcn_global_load_lds(
          (const __attribute__((address_space(1))) void*)g,
          (__attribute__((address_space(3))) void*)s, 16, 0, 0);
    }
#pragma unroll
    for (int i = 0; i < 4; ++i) {
      const int row = wave * 32 + i * 8 + lrow;
      const unsigned short* g = Wt + (size_t)(n0 + row) * 256 + k0 + (scol >> 1);
      unsigned short* s = Bs + (wave * 32 + i * 8) * 64;
      __builtin_amdgcn_global_load_lds(
          (const __attribute__((address_space(1))) void*)g,
          (__attribute__((address_space(3))) void*)s, 16, 0, 0);
    }
    __syncthreads();

    f16x8 af[4][2], bfr[4][2];
#pragma unroll
    for (int i = 0; i < 4; ++i) {
      const int row = wm * 64 + i * 16 + fr;
      const char* base = (const char*)As + row * 128;
#pragma unroll
      for (int kk = 0; kk < 2; ++kk)
        af[i][kk] = *(const f16x8*)(base + ((kk * 64 + fkb) ^ ((row & 7) << 4)));
    }
#pragma unroll
    for (int j = 0; j < 4; ++j) {
      const int row = wn * 64 + j * 16 + fr;
      const char* base = (const char*)Bs + row * 128;
#pragma unroll
      for (int kk = 0; kk < 2; ++kk)
        bfr[j][kk] = *(const f16x8*)(base + ((kk * 64 + fkb) ^ ((row & 7) << 4)));
    }
#pragma unroll
    for (int i = 0; i < 4; ++i)
#pragma unroll
      for (int j = 0; j < 4; ++j) {
        acc[i][j] = __builtin_amdgcn_mfma_f32_16x16x32_f16(af[i][0], bfr[j][0], acc[i][j], 0, 0, 0);
        acc[i][j] = __builtin_amdgcn_mfma_f32_16x16x32_f16(af[i][1], bfr[j][1], acc[i][j], 0, 0, 0);
      }
    __syncthreads();
  }

  const int fq = lane >> 4;
#pragma unroll
  for (int j = 0; j < 4; ++j) {
    const int n = n0 + wn * 64 + j * 16 + fr;
    const float bj = bsel[n - nsub];
#pragma unroll
    for (int i = 0; i < 4; ++i) {
#pragma unroll
      for (int r = 0; r < 4; ++r) {
        const int m = m0 + wm * 64 + i * 16 + fq * 4 + r;
        out16[(size_t)m * N + n] = f2h(acc[i][j][r] + bj);
      }
    }
  }
}

// ---------------------------------------------------------------------------
// Generic f16 MFMA GEMM (used for W1/relu): out = relu(A @ Wt^T + bias)
// ---------------------------------------------------------------------------
__global__ __launch_bounds__(256, 2) void gemm16_k(
    const unsigned short* __restrict__ A, const unsigned short* __restrict__ Wt,
    const float* __restrict__ bias, unsigned short* __restrict__ out16,
    int N, int relu)
{
  __shared__ unsigned short As[128 * 64];
  __shared__ unsigned short Bs[128 * 64];
  const int t = threadIdx.x;
  const int lane = t & 63, wave = t >> 6;
  const int wm = wave >> 1, wn = wave & 1;
  const int m0 = blockIdx.x * 128, n0 = blockIdx.y * 128;

  const int lrow = lane >> 3;
  const int pcol = (lane & 7) << 4;
  const int scol = pcol ^ (lrow << 4);

  f32x4v acc[4][4];
#pragma unroll
  for (int i = 0; i < 4; ++i)
#pragma unroll
    for (int j = 0; j < 4; ++j) acc[i][j] = (f32x4v){0.f, 0.f, 0.f, 0.f};

  const int fr = lane & 15;
  const int fkb = (lane >> 4) << 4;

  for (int k0 = 0; k0 < 256; k0 += 64) {
#pragma unroll
    for (int i = 0; i < 4; ++i) {
      const int row = wave * 32 + i * 8 + lrow;
      const unsigned short* g = A + (size_t)(m0 + row) * 256 + k0 + (scol >> 1);
      unsigned short* s = As + (wave * 32 + i * 8) * 64;
      __builtin_amdgcn_global_load_lds(
          (const __attribute__((address_space(1))) void*)g,
          (__attribute__((address_space(3))) void*)s, 16, 0, 0);
    }
#pragma unroll
    for (int i = 0; i < 4; ++i) {
      const int row = wave * 32 + i * 8 + lrow;
      const unsigned short* g = Wt + (size_t)(n0 + row) * 256 + k0 + (scol >> 1);
      unsigned short* s = Bs + (wave * 32 + i * 8) * 64;
      __builtin_amdgcn_global_load_lds(
          (const __attribute__((address_space(1))) void*)g,
          (__attribute__((address_space(3))) void*)s, 16, 0, 0);
    }
    __syncthreads();

    f16x8 af[4][2], bfr[4][2];
#pragma unroll
    for (int i = 0; i < 4; ++i) {
      const int row = wm * 64 + i * 16 + fr;
      const char* base = (const char*)As + row * 128;
#pragma unroll
      for (int kk = 0; kk < 2; ++kk)
        af[i][kk] = *(const f16x8*)(base + ((kk * 64 + fkb) ^ ((row & 7) << 4)));
    }
#pragma unroll
    for (int j = 0; j < 4; ++j) {
      const int row = wn * 64 + j * 16 + fr;
      const char* base = (const char*)Bs + row * 128;
#pragma unroll
      for (int kk = 0; kk < 2; ++kk)
        bfr[j][kk] = *(const f16x8*)(base + ((kk * 64 + fkb) ^ ((row & 7) << 4)));
    }
#pragma unroll
    for (int i = 0; i < 4; ++i)
#pragma unroll
      for (int j = 0; j < 4; ++j) {
        acc[i][j] = __builtin_amdgcn_mfma_f32_16x16x32_f16(af[i][0], bfr[j][0], acc[i][j], 0, 0, 0);
        acc[i][j] = __builtin_amdgcn_mfma_f32_16x16x32_f16(af[i][1], bfr[j][1], acc[i][j], 0, 0, 0);
      }
    __syncthreads();
  }

  const int fq = lane >> 4;
#pragma unroll
  for (int j = 0; j < 4; ++j) {
    const int n = n0 + wn * 64 + j * 16 + fr;
    const float bj = bias[n];
#pragma unroll
    for (int i = 0; i < 4; ++i) {
#pragma unroll
      for (int r = 0; r < 4; ++r) {
        const int m = m0 + wm * 64 + i * 16 + fq * 4 + r;
        float v = acc[i][j][r] + bj;
        if (relu) v = fmaxf(v, 0.f);
        out16[(size_t)m * N + n] = f2h(v);
      }
    }
  }
}

// ---------------------------------------------------------------------------
// Fused GEMM + residual + LayerNorm. out[M,256] = LN(A16@Wt^T + bias + res).
// BM=32, BN=256, BK=64, 512 thr (8 waves), grid M/32 = 680.
// ---------------------------------------------------------------------------
__global__ __launch_bounds__(512, 4) void gemm_ln_k(
    const unsigned short* __restrict__ A, const unsigned short* __restrict__ Wt,
    const float* __restrict__ bias, const float* __restrict__ res,
    const float* __restrict__ g, const float* __restrict__ b,
    float* __restrict__ outf, unsigned short* __restrict__ out16)
{
  __shared__ unsigned short As[32 * 64];          // 4 KB
  __shared__ unsigned short Bs[256 * 64 + 288];   // 32.5 KB; epilogue f32 [32][260]
  const int t = threadIdx.x;
  const int lane = t & 63, wave = t >> 6;
  const int rt = wave & 1, cg = wave >> 1;
  const int m0 = blockIdx.x * 32;

  const int lrow = lane >> 3;
  const int pcol = (lane & 7) << 4;
  const int scol = pcol ^ (lrow << 4);

  f32x4v acc[4];
#pragma unroll
  for (int j = 0; j < 4; ++j) acc[j] = (f32x4v){0.f, 0.f, 0.f, 0.f};

  const int fr = lane & 15;
  const int fq = lane >> 4;
  const int fkb = fq << 4;

  for (int k0 = 0; k0 < 256; k0 += 64) {
    if (wave < 4) {
      const int row = wave * 8 + lrow;
      const unsigned short* gp = A + (size_t)(m0 + row) * 256 + k0 + (scol >> 1);
      unsigned short* s = As + (wave * 8) * 64;
      __builtin_amdgcn_global_load_lds(
          (const __attribute__((address_space(1))) void*)gp,
          (__attribute__((address_space(3))) void*)s, 16, 0, 0);
    }
#pragma unroll
    for (int i = 0; i < 4; ++i) {
      const int row = wave * 32 + i * 8 + lrow;
      const unsigned short* gp = Wt + (size_t)row * 256 + k0 + (scol >> 1);
      unsigned short* s = Bs + (wave * 32 + i * 8) * 64;
      __builtin_amdgcn_global_load_lds(
          (const __attribute__((address_space(1))) void*)gp,
          (__attribute__((address_space(3))) void*)s, 16, 0, 0);
    }
    __syncthreads();

    f16x8 af0, af1;
    {
      const int arow = rt * 16 + fr;
      const char* abase = (const char*)As + arow * 128;
      af0 = *(const f16x8*)(abase + ((0 + fkb) ^ ((arow & 7) << 4)));
      af1 = *(const f16x8*)(abase + ((64 + fkb) ^ ((arow & 7) << 4)));
    }
#pragma unroll
    for (int j = 0; j < 4; ++j) {
      const int brow = cg * 64 + j * 16 + fr;
      const char* bbase = (const char*)Bs + brow * 128;
      const f16x8 b0 = *(const f16x8*)(bbase + ((0 + fkb) ^ ((brow & 7) << 4)));
      const f16x8 b1 = *(const f16x8*)(bbase + ((64 + fkb) ^ ((brow & 7) << 4)));
      acc[j] = __builtin_amdgcn_mfma_f32_16x16x32_f16(af0, b0, acc[j], 0, 0, 0);
      acc[j] = __builtin_amdgcn_mfma_f32_16x16x32_f16(af1, b1, acc[j], 0, 0, 0);
    }
    __syncthreads();
  }

  float* Cs = (float*)Bs;
#pragma unroll
  for (int j = 0; j < 4; ++j) {
    const int col = cg * 64 + j * 16 + fr;
#pragma unroll
    for (int rr = 0; rr < 4; ++rr) {
      const int row = rt * 16 + fq * 4 + rr;
      Cs[row * 260 + col] = acc[j][rr];
    }
  }
  __syncthreads();

  const int lg = lane >> 4, li = lane & 15;
  const int row = wave * 4 + lg;
  const size_t rowoff = (size_t)(m0 + row) * 256;

  float4 v[4];
  float s = 0.f;
#pragma unroll
  for (int c4 = 0; c4 < 4; ++c4) {
    const int col = c4 * 64 + li * 4;
    float4 x = *(float4*)&Cs[row * 260 + col];
    const float4 bi = *(const float4*)&bias[col];
    const float4 rv = *(const float4*)&res[rowoff + col];
    x.x += bi.x + rv.x; x.y += bi.y + rv.y;
    x.z += bi.z + rv.z; x.w += bi.w + rv.w;
    v[c4] = x;
    s += x.x + x.y + x.z + x.w;
  }
#pragma unroll
  for (int o = 1; o < 16; o <<= 1) s += __shfl_xor(s, o);
  const float mean = s * (1.f / 256.f);
  float ss = 0.f;
#pragma unroll
  for (int c4 = 0; c4 < 4; ++c4) {
    const float d0 = v[c4].x - mean, d1 = v[c4].y - mean;
    const float d2 = v[c4].z - mean, d3 = v[c4].w - mean;
    ss += d0 * d0 + d1 * d1 + d2 * d2 + d3 * d3;
  }
#pragma unroll
  for (int o = 1; o < 16; o <<= 1) ss += __shfl_xor(ss, o);
  const float rstd = rsqrtf(ss * (1.f / 256.f) + 1e-5f);

#pragma unroll
  for (int c4 = 0; c4 < 4; ++c4) {
    const int col = c4 * 64 + li * 4;
    const float4 gv = *(const float4*)&g[col];
    const float4 bv = *(const float4*)&b[col];
    float4 o4;
    o4.x = (v[c4].x - mean) * rstd * gv.x + bv.x;
    o4.y = (v[c4].y - mean) * rstd * gv.y + bv.y;
    o4.z = (v[c4].z - mean) * rstd * gv.z + bv.z;
    o4.w = (v[c4].w - mean) * rstd * gv.w + bv.w;
    if (outf) *(float4*)(outf + rowoff + col) = o4;
    if (out16) {
      ushort4 o;
      o.x = f2h(o4.x); o.y = f2h(o4.y); o.z = f2h(o4.z); o.w = f2h(o4.w);
      *(ushort4*)(out16 + rowoff + col) = o;
    }
  }
}

// ---------------------------------------------------------------------------
// Deformable sampling: 8 tokens/block, f16 value, fused softmax, f16 fused in.
// Gather loop uses (float)f16 -> v_fma_mix_f32.
// ---------------------------------------------------------------------------
__global__ __launch_bounds__(256) void samp_k(
    const unsigned short* __restrict__ value16, const unsigned short* __restrict__ fused16,
    const float* __restrict__ ref, unsigned short* __restrict__ att16)
{
  const int tok0 = blockIdx.x * 8;
  __shared__ half4v  swv[8][136];
  __shared__ short4v siv[8][136];
  const int t = threadIdx.x;
  const _Float16* fh = (const _Float16*)fused16;

#pragma unroll
  for (int it = 0; it < 4; ++it) {
    const int idx = it * 256 + t;
    const int ti = idx >> 7;
    const int e  = idx & 127;              // h*16 + lvl*4 + p
    const int tok = tok0 + ti;
    const int h = e >> 4;
    const int lvl = (e >> 2) & 3;
    const int HW[4] = {64, 32, 16, 8};
    const int LS[4] = {0, 4096, 5120, 5376};
    const int Wl = HW[lvl];

    const float lg = (float)fh[(size_t)tok * 384 + 256 + e];
    float mx = lg;
#pragma unroll
    for (int o = 1; o < 16; o <<= 1) mx = fmaxf(mx, __shfl_xor(mx, o, 16));
    const float ex = __expf(lg - mx);
    float sm = ex;
#pragma unroll
    for (int o = 1; o < 16; o <<= 1) sm += __shfl_xor(sm, o, 16);
    const float a = ex / sm;

    const float ox = (float)fh[(size_t)tok * 384 + e * 2 + 0];
    const float oy = (float)fh[(size_t)tok * 384 + e * 2 + 1];
    const float rx = ref[(size_t)tok * 8 + lvl * 2 + 0];
    const float ry = ref[(size_t)tok * 8 + lvl * 2 + 1];
    const float x = rx * (float)Wl + ox - 0.5f;
    const float y = ry * (float)Wl + oy - 0.5f;
    const float x0f = floorf(x), y0f = floorf(y);
    const float fx = x - x0f, fy = y - y0f;
    const int x0 = (int)x0f, y0 = (int)y0f;

    const int xi1 = x0 + 1, yi1 = y0 + 1;
    const float wx0 = 1.f - fx, wx1 = fx, wy0 = 1.f - fy, wy1 = fy;
    const int xc0 = min(max(x0, 0), Wl - 1), xc1 = min(max(xi1, 0), Wl - 1);
    const int yc0 = min(max(y0, 0), Wl - 1), yc1 = min(max(yi1, 0), Wl - 1);
    const bool vx0 = (x0 >= 0) & (x0 < Wl), vx1 = (xi1 >= 0) & (xi1 < Wl);
    const bool vy0 = (y0 >= 0) & (y0 < Wl), vy1 = (yi1 >= 0) & (yi1 < Wl);
    half4v hw;
    hw.x = (_Float16)((vx0 & vy0) ? a * wx0 * wy0 : 0.f);
    hw.y = (_Float16)((vx1 & vy0) ? a * wx1 * wy0 : 0.f);
    hw.z = (_Float16)((vx0 & vy1) ? a * wx0 * wy1 : 0.f);
    hw.w = (_Float16)((vx1 & vy1) ? a * wx1 * wy1 : 0.f);
    short4v hs;
    hs.x = (short)(LS[lvl] + yc0 * Wl + xc0);
    hs.y = (short)(LS[lvl] + yc0 * Wl + xc1);
    hs.z = (short)(LS[lvl] + yc1 * Wl + xc0);
    hs.w = (short)(LS[lvl] + yc1 * Wl + xc1);
    const int sl = e + h;
    swv[ti][sl] = hw;
    siv[ti][sl] = hs;
  }
  __syncthreads();

  const int wave = t >> 6, lane = t & 63;
  const int ti = wave * 2 + (lane >> 5);
  const int h = (lane >> 2) & 7, dg = lane & 3;
  const int tok = tok0 + ti;
  const int vbase = (tok / LQ_) * LQ_;
  const unsigned short* vb = value16 + (size_t)vbase * 256 + h * 32 + dg * 8;
  float acc[8] = {0.f, 0.f, 0.f, 0.f, 0.f, 0.f, 0.f, 0.f};
  const int ebase = h * 17;

#pragma unroll 4
  for (int p = 0; p < 16; ++p) {
    const half4v hw = swv[ti][ebase + p];
    const short4v hs = siv[ti][ebase + p];
    const float w0 = (float)hw.x, w1 = (float)hw.y, w2 = (float)hw.z, w3 = (float)hw.w;
    const uint4 u0 = *(const uint4*)(vb + (size_t)(int)hs.x * 256);
    const uint4 u1 = *(const uint4*)(vb + (size_t)(int)hs.y * 256);
    const uint4 u2 = *(const uint4*)(vb + (size_t)(int)hs.z * 256);
    const uint4 u3 = *(const uint4*)(vb + (size_t)(int)hs.w * 256);
#define ACC4(U, W) {                                              \
    const h2v p0 = __builtin_bit_cast(h2v, U.x);                  \
    const h2v p1 = __builtin_bit_cast(h2v, U.y);                  \
    const h2v p2 = __builtin_bit_cast(h2v, U.z);                  \
    const h2v p3 = __builtin_bit_cast(h2v, U.w);                  \
    acc[0] = fmaf(W, (float)p0[0], acc[0]);                       \
    acc[1] = fmaf(W, (float)p0[1], acc[1]);                       \
    acc[2] = fmaf(W, (float)p1[0], acc[2]);                       \
    acc[3] = fmaf(W, (float)p1[1], acc[3]);                       \
    acc[4] = fmaf(W, (float)p2[0], acc[4]);                       \
    acc[5] = fmaf(W, (float)p2[1], acc[5]);                       \
    acc[6] = fmaf(W, (float)p3[0], acc[6]);                       \
    acc[7] = fmaf(W, (float)p3[1], acc[7]); }
    ACC4(u0, w0) ACC4(u1, w1) ACC4(u2, w2) ACC4(u3, w3)
#undef ACC4
  }

  uint4 o;
  o.x = pack2h(acc[0], acc[1]);
  o.y = pack2h(acc[2], acc[3]);
  o.z = pack2h(acc[4], acc[5]);
  o.w = pack2h(acc[6], acc[7]);
  *(uint4*)(att16 + (size_t)tok * 256 + h * 32 + dg * 8) = o;
}

// ---------------------------------------------------------------------------
extern "C" void kernel_launch(void* const* d_in, const int* in_sizes, int n_in,
                              void* d_out, int out_size, void* d_ws, size_t ws_size,
                              hipStream_t stream)
{
  const float* src   = (const float*)d_in[0];
  const float* pos   = (const float*)d_in[1];
  const float* ref   = (const float*)d_in[2];
  const float* Wv    = (const float*)d_in[5];
  const float* bv    = (const float*)d_in[6];
  const float* Woff  = (const float*)d_in[7];
  const float* boff  = (const float*)d_in[8];
  const float* Wattn = (const float*)d_in[9];
  const float* battn = (const float*)d_in[10];
  const float* Wout  = (const float*)d_in[11];
  const float* bout  = (const float*)d_in[12];
  const float* g1    = (const float*)d_in[13];
  const float* b1    = (const float*)d_in[14];
  const float* W1    = (const float*)d_in[15];
  const float* bb1   = (const float*)d_in[16];
  const float* W2    = (const float*)d_in[17];
  const float* bb2   = (const float*)d_in[18];
  const float* g3    = (const float*)d_in[19];
  const float* b3    = (const float*)d_in[20];

  float* out = (float*)d_out;
  char* ws = (char*)d_ws;
  const size_t M = M_TOK;

  float* bufA = (float*)ws;                              // f32 M*256: value16 alias -> sxy f32
  unsigned short* fused16 = (unsigned short*)(ws + M * 256 * 4);  // f16 M*384
  unsigned short* bufE = fused16 + M * 384;              // f16 M*256: s16 -> att16 -> h16
  unsigned short* bufF = bufE + M * 256;                 // f16 M*256: q16 -> sxy16
  unsigned short* bufG = bufF + M * 256;                 // f16 weights (360448)
  unsigned short* value16 = (unsigned short*)bufA;       // f16 M*256, lifetime ends at samp

  unsigned short* WvT     = bufG + 0;
  unsigned short* WfusedT = bufG + 65536;
  unsigned short* WoutT   = bufG + 163840;
  unsigned short* W1T     = bufG + 229376;
  unsigned short* W2T     = bufG + 294912;

  const dim3 blk(256);

  prep_x<<<dim3(5440), blk, 0, stream>>>(src, pos, bufE, bufF);
  prep_w<<<dim3(1408), blk, 0, stream>>>(Wv, Woff, Wattn, Wout, W1, W2, bufG);

  // merged: value16 = s16@WvT+bv ; fused16 = q16@[Woff|Wattn]+[boff|battn]
  gemm_qkv_k<<<dim3(170, 5), blk, 0, stream>>>(bufE, bufF, WvT, WfusedT,
                                               bv, boff, battn, value16, fused16);
  // sampling (with in-kernel softmax) -> att16
  samp_k<<<dim3(2720), blk, 0, stream>>>(value16, fused16, ref, bufE);
  // sxy = LN(att @ Wout + bout + src) -> bufA f32 + bufF f16
  gemm_ln_k<<<dim3(680), dim3(512), 0, stream>>>(bufE, WoutT, bout, src, g1, b1, bufA, bufF);
  // h16 = f16(relu(sxy @ W1 + bb1))
  gemm16_k<<<dim3(170, 2), blk, 0, stream>>>(bufF, W1T, bb1, bufE, 256, 1);
  // out = LN(h @ W2 + bb2 + sxy)
  gemm_ln_k<<<dim3(680), dim3(512), 0, stream>>>(bufE, W2T, bb2, bufA, g3, b3, out, nullptr);
}

// Round 7
// 105.173 us; speedup vs baseline: 4.5838x; 1.1124x over previous
//
#include <hip/hip_runtime.h>
#include <cstddef>
#include <cstdint>

#define M_TOK 21760
#define LQ_ 5440

typedef _Float16 f16x8 __attribute__((ext_vector_type(8)));
typedef _Float16 h2v __attribute__((ext_vector_type(2)));
typedef float f32x4v __attribute__((ext_vector_type(4)));
typedef _Float16 half4v __attribute__((ext_vector_type(4)));

__device__ __forceinline__ unsigned short f2h(float f) {
  return __builtin_bit_cast(unsigned short, (_Float16)f);
}

// ---------------------------------------------------------------------------
// prep_k: blocks [0,5440): s16 = f16(src), q16 = f16(src+pos)
//         blocks [5440,6848): cast+transpose weights into G[n][k] f16 packed
// ---------------------------------------------------------------------------
__global__ __launch_bounds__(256) void prep_k(
    const float* __restrict__ src, const float* __restrict__ pos,
    const float* __restrict__ Wv, const float* __restrict__ Woff,
    const float* __restrict__ Wattn, const float* __restrict__ Wout,
    const float* __restrict__ W1, const float* __restrict__ W2,
    unsigned short* __restrict__ s16, unsigned short* __restrict__ q16,
    unsigned short* __restrict__ G)
{
  const int b = blockIdx.x;
  if (b < 5440) {
    const int i = b * 256 + threadIdx.x;
    const float4 s = ((const float4*)src)[i];
    const float4 p = ((const float4*)pos)[i];
    ushort4 a, q;
    a.x = f2h(s.x); a.y = f2h(s.y); a.z = f2h(s.z); a.w = f2h(s.w);
    q.x = f2h(s.x + p.x); q.y = f2h(s.y + p.y); q.z = f2h(s.z + p.z); q.w = f2h(s.w + p.w);
    ((ushort4*)s16)[i] = a;
    ((ushort4*)q16)[i] = q;
  } else {
    const int gid = (b - 5440) * 256 + threadIdx.x;
    const float* srcs[6] = {Wv, Woff, Wattn, Wout, W1, W2};
    const int starts[7] = {0, 65536, 131072, 163840, 229376, 294912, 360448};
    const int Nn[6] = {256, 256, 128, 256, 256, 256};
    int m = 0;
#pragma unroll
    for (int i = 1; i < 6; ++i) m += (gid >= starts[i]);
    const int local = gid - starts[m];
    const int n = local >> 8;
    const int k = local & 255;
    G[gid] = f2h(srcs[m][(size_t)k * Nn[m] + n]);
  }
}

// ---------------------------------------------------------------------------
// Merged first-stage GEMM: grid (170, 5).
//  by<2 : value = s16 @ WvT  (N=256) -> value16
//  by>=2: fused = q16 @ WfT  (N=384) -> fused16
// ---------------------------------------------------------------------------
__global__ __launch_bounds__(256, 2) void gemm_qkv_k(
    const unsigned short* __restrict__ s16, const unsigned short* __restrict__ q16,
    const unsigned short* __restrict__ WvT, const unsigned short* __restrict__ WfT,
    const float* __restrict__ bv, const float* __restrict__ boff,
    const float* __restrict__ battn,
    unsigned short* __restrict__ value16, unsigned short* __restrict__ fused16)
{
  const int by = blockIdx.y;
  const bool isv = (by < 2);
  const unsigned short* A  = isv ? s16 : q16;
  const unsigned short* Wt = isv ? WvT : WfT;
  const int n0 = isv ? by * 128 : (by - 2) * 128;
  const int N  = isv ? 256 : 384;
  unsigned short* out16 = isv ? value16 : fused16;
  const float* bsel; int nsub;
  if (isv)            { bsel = bv;    nsub = 0; }
  else if (n0 < 256)  { bsel = boff;  nsub = 0; }
  else                { bsel = battn; nsub = 256; }

  __shared__ unsigned short As[128 * 64];
  __shared__ unsigned short Bs[128 * 64];
  const int t = threadIdx.x;
  const int lane = t & 63, wave = t >> 6;
  const int wm = wave >> 1, wn = wave & 1;
  const int m0 = blockIdx.x * 128;

  const int lrow = lane >> 3;
  const int pcol = (lane & 7) << 4;
  const int scol = pcol ^ (lrow << 4);

  f32x4v acc[4][4];
#pragma unroll
  for (int i = 0; i < 4; ++i)
#pragma unroll
    for (int j = 0; j < 4; ++j) acc[i][j] = (f32x4v){0.f, 0.f, 0.f, 0.f};

  const int fr = lane & 15;
  const int fkb = (lane >> 4) << 4;

  for (int k0 = 0; k0 < 256; k0 += 64) {
#pragma unroll
    for (int i = 0; i < 4; ++i) {
      const int row = wave * 32 + i * 8 + lrow;
      const unsigned short* g = A + (size_t)(m0 + row) * 256 + k0 + (scol >> 1);
      unsigned short* s = As + (wave * 32 + i * 8) * 64;
      __builtin_amdgcn_global_load_lds(
          (const __attribute__((address_space(1))) void*)g,
          (__attribute__((address_space(3))) void*)s, 16, 0, 0);
    }
#pragma unroll
    for (int i = 0; i < 4; ++i) {
      const int row = wave * 32 + i * 8 + lrow;
      const unsigned short* g = Wt + (size_t)(n0 + row) * 256 + k0 + (scol >> 1);
      unsigned short* s = Bs + (wave * 32 + i * 8) * 64;
      __builtin_amdgcn_global_load_lds(
          (const __attribute__((address_space(1))) void*)g,
          (__attribute__((address_space(3))) void*)s, 16, 0, 0);
    }
    __syncthreads();

    f16x8 af[4][2], bfr[4][2];
#pragma unroll
    for (int i = 0; i < 4; ++i) {
      const int row = wm * 64 + i * 16 + fr;
      const char* base = (const char*)As + row * 128;
#pragma unroll
      for (int kk = 0; kk < 2; ++kk)
        af[i][kk] = *(const f16x8*)(base + ((kk * 64 + fkb) ^ ((row & 7) << 4)));
    }
#pragma unroll
    for (int j = 0; j < 4; ++j) {
      const int row = wn * 64 + j * 16 + fr;
      const char* base = (const char*)Bs + row * 128;
#pragma unroll
      for (int kk = 0; kk < 2; ++kk)
        bfr[j][kk] = *(const f16x8*)(base + ((kk * 64 + fkb) ^ ((row & 7) << 4)));
    }
#pragma unroll
    for (int i = 0; i < 4; ++i)
#pragma unroll
      for (int j = 0; j < 4; ++j) {
        acc[i][j] = __builtin_amdgcn_mfma_f32_16x16x32_f16(af[i][0], bfr[j][0], acc[i][j], 0, 0, 0);
        acc[i][j] = __builtin_amdgcn_mfma_f32_16x16x32_f16(af[i][1], bfr[j][1], acc[i][j], 0, 0, 0);
      }
    __syncthreads();
  }

  const int fq = lane >> 4;
#pragma unroll
  for (int j = 0; j < 4; ++j) {
    const int n = n0 + wn * 64 + j * 16 + fr;
    const float bj = bsel[n - nsub];
#pragma unroll
    for (int i = 0; i < 4; ++i) {
#pragma unroll
      for (int r = 0; r < 4; ++r) {
        const int m = m0 + wm * 64 + i * 16 + fq * 4 + r;
        out16[(size_t)m * N + n] = f2h(acc[i][j][r] + bj);
      }
    }
  }
}

// ---------------------------------------------------------------------------
// Generic f16 MFMA GEMM (used for W1/relu)
// ---------------------------------------------------------------------------
__global__ __launch_bounds__(256, 2) void gemm16_k(
    const unsigned short* __restrict__ A, const unsigned short* __restrict__ Wt,
    const float* __restrict__ bias, unsigned short* __restrict__ out16,
    int N, int relu)
{
  __shared__ unsigned short As[128 * 64];
  __shared__ unsigned short Bs[128 * 64];
  const int t = threadIdx.x;
  const int lane = t & 63, wave = t >> 6;
  const int wm = wave >> 1, wn = wave & 1;
  const int m0 = blockIdx.x * 128, n0 = blockIdx.y * 128;

  const int lrow = lane >> 3;
  const int pcol = (lane & 7) << 4;
  const int scol = pcol ^ (lrow << 4);

  f32x4v acc[4][4];
#pragma unroll
  for (int i = 0; i < 4; ++i)
#pragma unroll
    for (int j = 0; j < 4; ++j) acc[i][j] = (f32x4v){0.f, 0.f, 0.f, 0.f};

  const int fr = lane & 15;
  const int fkb = (lane >> 4) << 4;

  for (int k0 = 0; k0 < 256; k0 += 64) {
#pragma unroll
    for (int i = 0; i < 4; ++i) {
      const int row = wave * 32 + i * 8 + lrow;
      const unsigned short* g = A + (size_t)(m0 + row) * 256 + k0 + (scol >> 1);
      unsigned short* s = As + (wave * 32 + i * 8) * 64;
      __builtin_amdgcn_global_load_lds(
          (const __attribute__((address_space(1))) void*)g,
          (__attribute__((address_space(3))) void*)s, 16, 0, 0);
    }
#pragma unroll
    for (int i = 0; i < 4; ++i) {
      const int row = wave * 32 + i * 8 + lrow;
      const unsigned short* g = Wt + (size_t)(n0 + row) * 256 + k0 + (scol >> 1);
      unsigned short* s = Bs + (wave * 32 + i * 8) * 64;
      __builtin_amdgcn_global_load_lds(
          (const __attribute__((address_space(1))) void*)g,
          (__attribute__((address_space(3))) void*)s, 16, 0, 0);
    }
    __syncthreads();

    f16x8 af[4][2], bfr[4][2];
#pragma unroll
    for (int i = 0; i < 4; ++i) {
      const int row = wm * 64 + i * 16 + fr;
      const char* base = (const char*)As + row * 128;
#pragma unroll
      for (int kk = 0; kk < 2; ++kk)
        af[i][kk] = *(const f16x8*)(base + ((kk * 64 + fkb) ^ ((row & 7) << 4)));
    }
#pragma unroll
    for (int j = 0; j < 4; ++j) {
      const int row = wn * 64 + j * 16 + fr;
      const char* base = (const char*)Bs + row * 128;
#pragma unroll
      for (int kk = 0; kk < 2; ++kk)
        bfr[j][kk] = *(const f16x8*)(base + ((kk * 64 + fkb) ^ ((row & 7) << 4)));
    }
#pragma unroll
    for (int i = 0; i < 4; ++i)
#pragma unroll
      for (int j = 0; j < 4; ++j) {
        acc[i][j] = __builtin_amdgcn_mfma_f32_16x16x32_f16(af[i][0], bfr[j][0], acc[i][j], 0, 0, 0);
        acc[i][j] = __builtin_amdgcn_mfma_f32_16x16x32_f16(af[i][1], bfr[j][1], acc[i][j], 0, 0, 0);
      }
    __syncthreads();
  }

  const int fq = lane >> 4;
#pragma unroll
  for (int j = 0; j < 4; ++j) {
    const int n = n0 + wn * 64 + j * 16 + fr;
    const float bj = bias[n];
#pragma unroll
    for (int i = 0; i < 4; ++i) {
#pragma unroll
      for (int r = 0; r < 4; ++r) {
        const int m = m0 + wm * 64 + i * 16 + fq * 4 + r;
        float v = acc[i][j][r] + bj;
        if (relu) v = fmaxf(v, 0.f);
        out16[(size_t)m * N + n] = f2h(v);
      }
    }
  }
}

// ---------------------------------------------------------------------------
// Fused GEMM + residual + LayerNorm. BM=32, BN=256, 512 thr, grid 680.
// ---------------------------------------------------------------------------
__global__ __launch_bounds__(512, 4) void gemm_ln_k(
    const unsigned short* __restrict__ A, const unsigned short* __restrict__ Wt,
    const float* __restrict__ bias, const float* __restrict__ res,
    const float* __restrict__ g, const float* __restrict__ b,
    float* __restrict__ outf, unsigned short* __restrict__ out16)
{
  __shared__ unsigned short As[32 * 64];
  __shared__ unsigned short Bs[256 * 64 + 288];
  const int t = threadIdx.x;
  const int lane = t & 63, wave = t >> 6;
  const int rt = wave & 1, cg = wave >> 1;
  const int m0 = blockIdx.x * 32;

  const int lrow = lane >> 3;
  const int pcol = (lane & 7) << 4;
  const int scol = pcol ^ (lrow << 4);

  f32x4v acc[4];
#pragma unroll
  for (int j = 0; j < 4; ++j) acc[j] = (f32x4v){0.f, 0.f, 0.f, 0.f};

  const int fr = lane & 15;
  const int fq = lane >> 4;
  const int fkb = fq << 4;

  for (int k0 = 0; k0 < 256; k0 += 64) {
    if (wave < 4) {
      const int row = wave * 8 + lrow;
      const unsigned short* gp = A + (size_t)(m0 + row) * 256 + k0 + (scol >> 1);
      unsigned short* s = As + (wave * 8) * 64;
      __builtin_amdgcn_global_load_lds(
          (const __attribute__((address_space(1))) void*)gp,
          (__attribute__((address_space(3))) void*)s, 16, 0, 0);
    }
#pragma unroll
    for (int i = 0; i < 4; ++i) {
      const int row = wave * 32 + i * 8 + lrow;
      const unsigned short* gp = Wt + (size_t)row * 256 + k0 + (scol >> 1);
      unsigned short* s = Bs + (wave * 32 + i * 8) * 64;
      __builtin_amdgcn_global_load_lds(
          (const __attribute__((address_space(1))) void*)gp,
          (__attribute__((address_space(3))) void*)s, 16, 0, 0);
    }
    __syncthreads();

    f16x8 af0, af1;
    {
      const int arow = rt * 16 + fr;
      const char* abase = (const char*)As + arow * 128;
      af0 = *(const f16x8*)(abase + ((0 + fkb) ^ ((arow & 7) << 4)));
      af1 = *(const f16x8*)(abase + ((64 + fkb) ^ ((arow & 7) << 4)));
    }
#pragma unroll
    for (int j = 0; j < 4; ++j) {
      const int brow = cg * 64 + j * 16 + fr;
      const char* bbase = (const char*)Bs + brow * 128;
      const f16x8 b0 = *(const f16x8*)(bbase + ((0 + fkb) ^ ((brow & 7) << 4)));
      const f16x8 b1 = *(const f16x8*)(bbase + ((64 + fkb) ^ ((brow & 7) << 4)));
      acc[j] = __builtin_amdgcn_mfma_f32_16x16x32_f16(af0, b0, acc[j], 0, 0, 0);
      acc[j] = __builtin_amdgcn_mfma_f32_16x16x32_f16(af1, b1, acc[j], 0, 0, 0);
    }
    __syncthreads();
  }

  float* Cs = (float*)Bs;
#pragma unroll
  for (int j = 0; j < 4; ++j) {
    const int col = cg * 64 + j * 16 + fr;
#pragma unroll
    for (int rr = 0; rr < 4; ++rr) {
      const int row = rt * 16 + fq * 4 + rr;
      Cs[row * 260 + col] = acc[j][rr];
    }
  }
  __syncthreads();

  const int lg = lane >> 4, li = lane & 15;
  const int row = wave * 4 + lg;
  const size_t rowoff = (size_t)(m0 + row) * 256;

  float4 v[4];
  float s = 0.f;
#pragma unroll
  for (int c4 = 0; c4 < 4; ++c4) {
    const int col = c4 * 64 + li * 4;
    float4 x = *(float4*)&Cs[row * 260 + col];
    const float4 bi = *(const float4*)&bias[col];
    const float4 rv = *(const float4*)&res[rowoff + col];
    x.x += bi.x + rv.x; x.y += bi.y + rv.y;
    x.z += bi.z + rv.z; x.w += bi.w + rv.w;
    v[c4] = x;
    s += x.x + x.y + x.z + x.w;
  }
#pragma unroll
  for (int o = 1; o < 16; o <<= 1) s += __shfl_xor(s, o);
  const float mean = s * (1.f / 256.f);
  float ss = 0.f;
#pragma unroll
  for (int c4 = 0; c4 < 4; ++c4) {
    const float d0 = v[c4].x - mean, d1 = v[c4].y - mean;
    const float d2 = v[c4].z - mean, d3 = v[c4].w - mean;
    ss += d0 * d0 + d1 * d1 + d2 * d2 + d3 * d3;
  }
#pragma unroll
  for (int o = 1; o < 16; o <<= 1) ss += __shfl_xor(ss, o);
  const float rstd = rsqrtf(ss * (1.f / 256.f) + 1e-5f);

#pragma unroll
  for (int c4 = 0; c4 < 4; ++c4) {
    const int col = c4 * 64 + li * 4;
    const float4 gv = *(const float4*)&g[col];
    const float4 bv = *(const float4*)&b[col];
    float4 o4;
    o4.x = (v[c4].x - mean) * rstd * gv.x + bv.x;
    o4.y = (v[c4].y - mean) * rstd * gv.y + bv.y;
    o4.z = (v[c4].z - mean) * rstd * gv.z + bv.z;
    o4.w = (v[c4].w - mean) * rstd * gv.w + bv.w;
    if (outf) *(float4*)(outf + rowoff + col) = o4;
    if (out16) {
      ushort4 o;
      o.x = f2h(o4.x); o.y = f2h(o4.y); o.z = f2h(o4.z); o.w = f2h(o4.w);
      *(ushort4*)(out16 + rowoff + col) = o;
    }
  }
}

// ---------------------------------------------------------------------------
// Deformable sampling v4: packed f16 accum (v_pk_fma_f16) + premultiplied
// byte offsets + SGPR-base gathers. 8 tokens/block; LDS 26.1 KB -> 6 blk/CU.
// ---------------------------------------------------------------------------
__global__ __launch_bounds__(256) void samp_k(
    const unsigned short* __restrict__ value16, const unsigned short* __restrict__ fused16,
    const float* __restrict__ ref, unsigned short* __restrict__ att16)
{
  const int tok0 = blockIdx.x * 8;
  __shared__ half4v swv[8][136];   // 8.7 KB: 4 corner weights (f16)
  __shared__ int4   siv[8][136];   // 17.4 KB: 4 corner byte offsets (idx*512)
  const int t = threadIdx.x;
  const _Float16* fh = (const _Float16*)fused16;

#pragma unroll
  for (int it = 0; it < 4; ++it) {
    const int idx = it * 256 + t;
    const int ti = idx >> 7;
    const int e  = idx & 127;              // h*16 + lvl*4 + p
    const int tok = tok0 + ti;
    const int h = e >> 4;
    const int lvl = (e >> 2) & 3;
    const int HW[4] = {64, 32, 16, 8};
    const int LS[4] = {0, 4096, 5120, 5376};
    const int Wl = HW[lvl];

    const float lg = (float)fh[(size_t)tok * 384 + 256 + e];
    float mx = lg;
#pragma unroll
    for (int o = 1; o < 16; o <<= 1) mx = fmaxf(mx, __shfl_xor(mx, o, 16));
    const float ex = __expf(lg - mx);
    float sm = ex;
#pragma unroll
    for (int o = 1; o < 16; o <<= 1) sm += __shfl_xor(sm, o, 16);
    const float a = ex / sm;

    const float ox = (float)fh[(size_t)tok * 384 + e * 2 + 0];
    const float oy = (float)fh[(size_t)tok * 384 + e * 2 + 1];
    const float rx = ref[(size_t)tok * 8 + lvl * 2 + 0];
    const float ry = ref[(size_t)tok * 8 + lvl * 2 + 1];
    const float x = rx * (float)Wl + ox - 0.5f;
    const float y = ry * (float)Wl + oy - 0.5f;
    const float x0f = floorf(x), y0f = floorf(y);
    const float fx = x - x0f, fy = y - y0f;
    const int x0 = (int)x0f, y0 = (int)y0f;

    const int xi1 = x0 + 1, yi1 = y0 + 1;
    const float wx0 = 1.f - fx, wx1 = fx, wy0 = 1.f - fy, wy1 = fy;
    const int xc0 = min(max(x0, 0), Wl - 1), xc1 = min(max(xi1, 0), Wl - 1);
    const int yc0 = min(max(y0, 0), Wl - 1), yc1 = min(max(yi1, 0), Wl - 1);
    const bool vx0 = (x0 >= 0) & (x0 < Wl), vx1 = (xi1 >= 0) & (xi1 < Wl);
    const bool vy0 = (y0 >= 0) & (y0 < Wl), vy1 = (yi1 >= 0) & (yi1 < Wl);
    half4v hw;
    hw.x = (_Float16)((vx0 & vy0) ? a * wx0 * wy0 : 0.f);
    hw.y = (_Float16)((vx1 & vy0) ? a * wx1 * wy0 : 0.f);
    hw.z = (_Float16)((vx0 & vy1) ? a * wx0 * wy1 : 0.f);
    hw.w = (_Float16)((vx1 & vy1) ? a * wx1 * wy1 : 0.f);
    int4 io;
    io.x = (LS[lvl] + yc0 * Wl + xc0) << 9;   // *512 B per row
    io.y = (LS[lvl] + yc0 * Wl + xc1) << 9;
    io.z = (LS[lvl] + yc1 * Wl + xc0) << 9;
    io.w = (LS[lvl] + yc1 * Wl + xc1) << 9;
    const int sl = e + h;
    swv[ti][sl] = hw;
    siv[ti][sl] = io;
  }
  __syncthreads();

  const int wave = t >> 6, lane = t & 63;
  const int ti = wave * 2 + (lane >> 5);
  const int h = (lane >> 2) & 7, dg = lane & 3;
  const int tok = tok0 + ti;
  const int vbase = (tok0 / LQ_) * LQ_;              // block-uniform (5440%8==0)
  const char* vb = (const char*)(value16 + (size_t)vbase * 256);
  const int laneoff = h * 64 + dg * 16;
  h2v a0 = {0, 0}, a1 = {0, 0}, a2 = {0, 0}, a3 = {0, 0};
  const int ebase = h * 17;

#pragma unroll 4
  for (int p = 0; p < 16; ++p) {
    const half4v hw = swv[ti][ebase + p];
    const int4 io = siv[ti][ebase + p];
    const uint4 u0 = *(const uint4*)(vb + (io.x + laneoff));
    const uint4 u1 = *(const uint4*)(vb + (io.y + laneoff));
    const uint4 u2 = *(const uint4*)(vb + (io.z + laneoff));
    const uint4 u3 = *(const uint4*)(vb + (io.w + laneoff));
#define CORNER(U, WI) {                                            \
    const h2v w2 = __builtin_shufflevector(hw, hw, WI, WI);        \
    a0 += w2 * __builtin_bit_cast(h2v, U.x);                       \
    a1 += w2 * __builtin_bit_cast(h2v, U.y);                       \
    a2 += w2 * __builtin_bit_cast(h2v, U.z);                       \
    a3 += w2 * __builtin_bit_cast(h2v, U.w); }
    CORNER(u0, 0) CORNER(u1, 1) CORNER(u2, 2) CORNER(u3, 3)
#undef CORNER
  }

  uint4 o;
  o.x = __builtin_bit_cast(unsigned, a0);
  o.y = __builtin_bit_cast(unsigned, a1);
  o.z = __builtin_bit_cast(unsigned, a2);
  o.w = __builtin_bit_cast(unsigned, a3);
  *(uint4*)(att16 + (size_t)tok * 256 + h * 32 + dg * 8) = o;
}

// ---------------------------------------------------------------------------
extern "C" void kernel_launch(void* const* d_in, const int* in_sizes, int n_in,
                              void* d_out, int out_size, void* d_ws, size_t ws_size,
                              hipStream_t stream)
{
  const float* src   = (const float*)d_in[0];
  const float* pos   = (const float*)d_in[1];
  const float* ref   = (const float*)d_in[2];
  const float* Wv    = (const float*)d_in[5];
  const float* bv    = (const float*)d_in[6];
  const float* Woff  = (const float*)d_in[7];
  const float* boff  = (const float*)d_in[8];
  const float* Wattn = (const float*)d_in[9];
  const float* battn = (const float*)d_in[10];
  const float* Wout  = (const float*)d_in[11];
  const float* bout  = (const float*)d_in[12];
  const float* g1    = (const float*)d_in[13];
  const float* b1    = (const float*)d_in[14];
  const float* W1    = (const float*)d_in[15];
  const float* bb1   = (const float*)d_in[16];
  const float* W2    = (const float*)d_in[17];
  const float* bb2   = (const float*)d_in[18];
  const float* g3    = (const float*)d_in[19];
  const float* b3    = (const float*)d_in[20];

  float* out = (float*)d_out;
  char* ws = (char*)d_ws;
  const size_t M = M_TOK;

  float* bufA = (float*)ws;                              // f32 M*256: value16 alias -> sxy f32
  unsigned short* fused16 = (unsigned short*)(ws + M * 256 * 4);  // f16 M*384
  unsigned short* bufE = fused16 + M * 384;              // f16 M*256: s16 -> att16 -> h16
  unsigned short* bufF = bufE + M * 256;                 // f16 M*256: q16 -> sxy16
  unsigned short* bufG = bufF + M * 256;                 // f16 weights (360448)
  unsigned short* value16 = (unsigned short*)bufA;       // f16 M*256, ends at samp

  unsigned short* WvT     = bufG + 0;
  unsigned short* WfusedT = bufG + 65536;
  unsigned short* WoutT   = bufG + 163840;
  unsigned short* W1T     = bufG + 229376;
  unsigned short* W2T     = bufG + 294912;

  const dim3 blk(256);

  prep_k<<<dim3(6848), blk, 0, stream>>>(src, pos, Wv, Woff, Wattn, Wout, W1, W2,
                                         bufE, bufF, bufG);
  // value16 = s16@WvT+bv ; fused16 = q16@[Woff|Wattn]+[boff|battn]
  gemm_qkv_k<<<dim3(170, 5), blk, 0, stream>>>(bufE, bufF, WvT, WfusedT,
                                               bv, boff, battn, value16, fused16);
  // sampling (with in-kernel softmax) -> att16
  samp_k<<<dim3(2720), blk, 0, stream>>>(value16, fused16, ref, bufE);
  // sxy = LN(att @ Wout + bout + src) -> bufA f32 + bufF f16
  gemm_ln_k<<<dim3(680), dim3(512), 0, stream>>>(bufE, WoutT, bout, src, g1, b1, bufA, bufF);
  // h16 = f16(relu(sxy @ W1 + bb1))
  gemm16_k<<<dim3(170, 2), blk, 0, stream>>>(bufF, W1T, bb1, bufE, 256, 1);
  // out = LN(h @ W2 + bb2 + sxy)
  gemm_ln_k<<<dim3(680), dim3(512), 0, stream>>>(bufE, W2T, bb2, bufA, g3, b3, out, nullptr);
}

// Round 8
// 102.605 us; speedup vs baseline: 4.6985x; 1.0250x over previous
//
#include <hip/hip_runtime.h>
#include <cstddef>
#include <cstdint>

#define M_TOK 21760
#define LQ_ 5440

typedef _Float16 f16x8 __attribute__((ext_vector_type(8)));
typedef _Float16 h2v __attribute__((ext_vector_type(2)));
typedef float f32x4v __attribute__((ext_vector_type(4)));
typedef _Float16 half4v __attribute__((ext_vector_type(4)));

__device__ __forceinline__ unsigned short f2h(float f) {
  return __builtin_bit_cast(unsigned short, (_Float16)f);
}

// ---------------------------------------------------------------------------
// prep_k: blocks [0,5440): s16 = f16(src), q16 = f16(src+pos)
//         blocks [5440,6848): cast+transpose weights into G[n][k] f16 packed
// ---------------------------------------------------------------------------
__global__ __launch_bounds__(256) void prep_k(
    const float* __restrict__ src, const float* __restrict__ pos,
    const float* __restrict__ Wv, const float* __restrict__ Woff,
    const float* __restrict__ Wattn, const float* __restrict__ Wout,
    const float* __restrict__ W1, const float* __restrict__ W2,
    unsigned short* __restrict__ s16, unsigned short* __restrict__ q16,
    unsigned short* __restrict__ G)
{
  const int b = blockIdx.x;
  if (b < 5440) {
    const int i = b * 256 + threadIdx.x;
    const float4 s = ((const float4*)src)[i];
    const float4 p = ((const float4*)pos)[i];
    ushort4 a, q;
    a.x = f2h(s.x); a.y = f2h(s.y); a.z = f2h(s.z); a.w = f2h(s.w);
    q.x = f2h(s.x + p.x); q.y = f2h(s.y + p.y); q.z = f2h(s.z + p.z); q.w = f2h(s.w + p.w);
    ((ushort4*)s16)[i] = a;
    ((ushort4*)q16)[i] = q;
  } else {
    const int gid = (b - 5440) * 256 + threadIdx.x;
    const float* srcs[6] = {Wv, Woff, Wattn, Wout, W1, W2};
    const int starts[7] = {0, 65536, 131072, 163840, 229376, 294912, 360448};
    const int Nn[6] = {256, 256, 128, 256, 256, 256};
    int m = 0;
#pragma unroll
    for (int i = 1; i < 6; ++i) m += (gid >= starts[i]);
    const int local = gid - starts[m];
    const int n = local >> 8;
    const int k = local & 255;
    G[gid] = f2h(srcs[m][(size_t)k * Nn[m] + n]);
  }
}

// ---------------------------------------------------------------------------
// Merged first-stage GEMM: grid (170, 5).
//  by<2 : value = s16 @ WvT  (N=256) -> value16
//  by>=2: fused = q16 @ WfT  (N=384) -> fused16
// ---------------------------------------------------------------------------
__global__ __launch_bounds__(256, 2) void gemm_qkv_k(
    const unsigned short* __restrict__ s16, const unsigned short* __restrict__ q16,
    const unsigned short* __restrict__ WvT, const unsigned short* __restrict__ WfT,
    const float* __restrict__ bv, const float* __restrict__ boff,
    const float* __restrict__ battn,
    unsigned short* __restrict__ value16, unsigned short* __restrict__ fused16)
{
  const int by = blockIdx.y;
  const bool isv = (by < 2);
  const unsigned short* A  = isv ? s16 : q16;
  const unsigned short* Wt = isv ? WvT : WfT;
  const int n0 = isv ? by * 128 : (by - 2) * 128;
  const int N  = isv ? 256 : 384;
  unsigned short* out16 = isv ? value16 : fused16;
  const float* bsel; int nsub;
  if (isv)            { bsel = bv;    nsub = 0; }
  else if (n0 < 256)  { bsel = boff;  nsub = 0; }
  else                { bsel = battn; nsub = 256; }

  __shared__ unsigned short As[128 * 64];
  __shared__ unsigned short Bs[128 * 64];
  const int t = threadIdx.x;
  const int lane = t & 63, wave = t >> 6;
  const int wm = wave >> 1, wn = wave & 1;
  const int m0 = blockIdx.x * 128;

  const int lrow = lane >> 3;
  const int pcol = (lane & 7) << 4;
  const int scol = pcol ^ (lrow << 4);

  f32x4v acc[4][4];
#pragma unroll
  for (int i = 0; i < 4; ++i)
#pragma unroll
    for (int j = 0; j < 4; ++j) acc[i][j] = (f32x4v){0.f, 0.f, 0.f, 0.f};

  const int fr = lane & 15;
  const int fkb = (lane >> 4) << 4;

  for (int k0 = 0; k0 < 256; k0 += 64) {
#pragma unroll
    for (int i = 0; i < 4; ++i) {
      const int row = wave * 32 + i * 8 + lrow;
      const unsigned short* g = A + (size_t)(m0 + row) * 256 + k0 + (scol >> 1);
      unsigned short* s = As + (wave * 32 + i * 8) * 64;
      __builtin_amdgcn_global_load_lds(
          (const __attribute__((address_space(1))) void*)g,
          (__attribute__((address_space(3))) void*)s, 16, 0, 0);
    }
#pragma unroll
    for (int i = 0; i < 4; ++i) {
      const int row = wave * 32 + i * 8 + lrow;
      const unsigned short* g = Wt + (size_t)(n0 + row) * 256 + k0 + (scol >> 1);
      unsigned short* s = Bs + (wave * 32 + i * 8) * 64;
      __builtin_amdgcn_global_load_lds(
          (const __attribute__((address_space(1))) void*)g,
          (__attribute__((address_space(3))) void*)s, 16, 0, 0);
    }
    __syncthreads();

    f16x8 af[4][2], bfr[4][2];
#pragma unroll
    for (int i = 0; i < 4; ++i) {
      const int row = wm * 64 + i * 16 + fr;
      const char* base = (const char*)As + row * 128;
#pragma unroll
      for (int kk = 0; kk < 2; ++kk)
        af[i][kk] = *(const f16x8*)(base + ((kk * 64 + fkb) ^ ((row & 7) << 4)));
    }
#pragma unroll
    for (int j = 0; j < 4; ++j) {
      const int row = wn * 64 + j * 16 + fr;
      const char* base = (const char*)Bs + row * 128;
#pragma unroll
      for (int kk = 0; kk < 2; ++kk)
        bfr[j][kk] = *(const f16x8*)(base + ((kk * 64 + fkb) ^ ((row & 7) << 4)));
    }
#pragma unroll
    for (int i = 0; i < 4; ++i)
#pragma unroll
      for (int j = 0; j < 4; ++j) {
        acc[i][j] = __builtin_amdgcn_mfma_f32_16x16x32_f16(af[i][0], bfr[j][0], acc[i][j], 0, 0, 0);
        acc[i][j] = __builtin_amdgcn_mfma_f32_16x16x32_f16(af[i][1], bfr[j][1], acc[i][j], 0, 0, 0);
      }
    __syncthreads();
  }

  const int fq = lane >> 4;
#pragma unroll
  for (int j = 0; j < 4; ++j) {
    const int n = n0 + wn * 64 + j * 16 + fr;
    const float bj = bsel[n - nsub];
#pragma unroll
    for (int i = 0; i < 4; ++i) {
#pragma unroll
      for (int r = 0; r < 4; ++r) {
        const int m = m0 + wm * 64 + i * 16 + fq * 4 + r;
        out16[(size_t)m * N + n] = f2h(acc[i][j][r] + bj);
      }
    }
  }
}

// ---------------------------------------------------------------------------
// Generic f16 MFMA GEMM (used for W1/relu)
// ---------------------------------------------------------------------------
__global__ __launch_bounds__(256, 2) void gemm16_k(
    const unsigned short* __restrict__ A, const unsigned short* __restrict__ Wt,
    const float* __restrict__ bias, unsigned short* __restrict__ out16,
    int N, int relu)
{
  __shared__ unsigned short As[128 * 64];
  __shared__ unsigned short Bs[128 * 64];
  const int t = threadIdx.x;
  const int lane = t & 63, wave = t >> 6;
  const int wm = wave >> 1, wn = wave & 1;
  const int m0 = blockIdx.x * 128, n0 = blockIdx.y * 128;

  const int lrow = lane >> 3;
  const int pcol = (lane & 7) << 4;
  const int scol = pcol ^ (lrow << 4);

  f32x4v acc[4][4];
#pragma unroll
  for (int i = 0; i < 4; ++i)
#pragma unroll
    for (int j = 0; j < 4; ++j) acc[i][j] = (f32x4v){0.f, 0.f, 0.f, 0.f};

  const int fr = lane & 15;
  const int fkb = (lane >> 4) << 4;

  for (int k0 = 0; k0 < 256; k0 += 64) {
#pragma unroll
    for (int i = 0; i < 4; ++i) {
      const int row = wave * 32 + i * 8 + lrow;
      const unsigned short* g = A + (size_t)(m0 + row) * 256 + k0 + (scol >> 1);
      unsigned short* s = As + (wave * 32 + i * 8) * 64;
      __builtin_amdgcn_global_load_lds(
          (const __attribute__((address_space(1))) void*)g,
          (__attribute__((address_space(3))) void*)s, 16, 0, 0);
    }
#pragma unroll
    for (int i = 0; i < 4; ++i) {
      const int row = wave * 32 + i * 8 + lrow;
      const unsigned short* g = Wt + (size_t)(n0 + row) * 256 + k0 + (scol >> 1);
      unsigned short* s = Bs + (wave * 32 + i * 8) * 64;
      __builtin_amdgcn_global_load_lds(
          (const __attribute__((address_space(1))) void*)g,
          (__attribute__((address_space(3))) void*)s, 16, 0, 0);
    }
    __syncthreads();

    f16x8 af[4][2], bfr[4][2];
#pragma unroll
    for (int i = 0; i < 4; ++i) {
      const int row = wm * 64 + i * 16 + fr;
      const char* base = (const char*)As + row * 128;
#pragma unroll
      for (int kk = 0; kk < 2; ++kk)
        af[i][kk] = *(const f16x8*)(base + ((kk * 64 + fkb) ^ ((row & 7) << 4)));
    }
#pragma unroll
    for (int j = 0; j < 4; ++j) {
      const int row = wn * 64 + j * 16 + fr;
      const char* base = (const char*)Bs + row * 128;
#pragma unroll
      for (int kk = 0; kk < 2; ++kk)
        bfr[j][kk] = *(const f16x8*)(base + ((kk * 64 + fkb) ^ ((row & 7) << 4)));
    }
#pragma unroll
    for (int i = 0; i < 4; ++i)
#pragma unroll
      for (int j = 0; j < 4; ++j) {
        acc[i][j] = __builtin_amdgcn_mfma_f32_16x16x32_f16(af[i][0], bfr[j][0], acc[i][j], 0, 0, 0);
        acc[i][j] = __builtin_amdgcn_mfma_f32_16x16x32_f16(af[i][1], bfr[j][1], acc[i][j], 0, 0, 0);
      }
    __syncthreads();
  }

  const int fq = lane >> 4;
#pragma unroll
  for (int j = 0; j < 4; ++j) {
    const int n = n0 + wn * 64 + j * 16 + fr;
    const float bj = bias[n];
#pragma unroll
    for (int i = 0; i < 4; ++i) {
#pragma unroll
      for (int r = 0; r < 4; ++r) {
        const int m = m0 + wm * 64 + i * 16 + fq * 4 + r;
        float v = acc[i][j][r] + bj;
        if (relu) v = fmaxf(v, 0.f);
        out16[(size_t)m * N + n] = f2h(v);
      }
    }
  }
}

// ---------------------------------------------------------------------------
// Fused GEMM + residual + LayerNorm. BM=32, BN=256, 512 thr, grid 680.
// ---------------------------------------------------------------------------
__global__ __launch_bounds__(512, 4) void gemm_ln_k(
    const unsigned short* __restrict__ A, const unsigned short* __restrict__ Wt,
    const float* __restrict__ bias, const float* __restrict__ res,
    const float* __restrict__ g, const float* __restrict__ b,
    float* __restrict__ outf, unsigned short* __restrict__ out16)
{
  __shared__ unsigned short As[32 * 64];
  __shared__ unsigned short Bs[256 * 64 + 288];
  const int t = threadIdx.x;
  const int lane = t & 63, wave = t >> 6;
  const int rt = wave & 1, cg = wave >> 1;
  const int m0 = blockIdx.x * 32;

  const int lrow = lane >> 3;
  const int pcol = (lane & 7) << 4;
  const int scol = pcol ^ (lrow << 4);

  f32x4v acc[4];
#pragma unroll
  for (int j = 0; j < 4; ++j) acc[j] = (f32x4v){0.f, 0.f, 0.f, 0.f};

  const int fr = lane & 15;
  const int fq = lane >> 4;
  const int fkb = fq << 4;

  for (int k0 = 0; k0 < 256; k0 += 64) {
    if (wave < 4) {
      const int row = wave * 8 + lrow;
      const unsigned short* gp = A + (size_t)(m0 + row) * 256 + k0 + (scol >> 1);
      unsigned short* s = As + (wave * 8) * 64;
      __builtin_amdgcn_global_load_lds(
          (const __attribute__((address_space(1))) void*)gp,
          (__attribute__((address_space(3))) void*)s, 16, 0, 0);
    }
#pragma unroll
    for (int i = 0; i < 4; ++i) {
      const int row = wave * 32 + i * 8 + lrow;
      const unsigned short* gp = Wt + (size_t)row * 256 + k0 + (scol >> 1);
      unsigned short* s = Bs + (wave * 32 + i * 8) * 64;
      __builtin_amdgcn_global_load_lds(
          (const __attribute__((address_space(1))) void*)gp,
          (__attribute__((address_space(3))) void*)s, 16, 0, 0);
    }
    __syncthreads();

    f16x8 af0, af1;
    {
      const int arow = rt * 16 + fr;
      const char* abase = (const char*)As + arow * 128;
      af0 = *(const f16x8*)(abase + ((0 + fkb) ^ ((arow & 7) << 4)));
      af1 = *(const f16x8*)(abase + ((64 + fkb) ^ ((arow & 7) << 4)));
    }
#pragma unroll
    for (int j = 0; j < 4; ++j) {
      const int brow = cg * 64 + j * 16 + fr;
      const char* bbase = (const char*)Bs + brow * 128;
      const f16x8 b0 = *(const f16x8*)(bbase + ((0 + fkb) ^ ((brow & 7) << 4)));
      const f16x8 b1 = *(const f16x8*)(bbase + ((64 + fkb) ^ ((brow & 7) << 4)));
      acc[j] = __builtin_amdgcn_mfma_f32_16x16x32_f16(af0, b0, acc[j], 0, 0, 0);
      acc[j] = __builtin_amdgcn_mfma_f32_16x16x32_f16(af1, b1, acc[j], 0, 0, 0);
    }
    __syncthreads();
  }

  float* Cs = (float*)Bs;
#pragma unroll
  for (int j = 0; j < 4; ++j) {
    const int col = cg * 64 + j * 16 + fr;
#pragma unroll
    for (int rr = 0; rr < 4; ++rr) {
      const int row = rt * 16 + fq * 4 + rr;
      Cs[row * 260 + col] = acc[j][rr];
    }
  }
  __syncthreads();

  const int lg = lane >> 4, li = lane & 15;
  const int row = wave * 4 + lg;
  const size_t rowoff = (size_t)(m0 + row) * 256;

  float4 v[4];
  float s = 0.f;
#pragma unroll
  for (int c4 = 0; c4 < 4; ++c4) {
    const int col = c4 * 64 + li * 4;
    float4 x = *(float4*)&Cs[row * 260 + col];
    const float4 bi = *(const float4*)&bias[col];
    const float4 rv = *(const float4*)&res[rowoff + col];
    x.x += bi.x + rv.x; x.y += bi.y + rv.y;
    x.z += bi.z + rv.z; x.w += bi.w + rv.w;
    v[c4] = x;
    s += x.x + x.y + x.z + x.w;
  }
#pragma unroll
  for (int o = 1; o < 16; o <<= 1) s += __shfl_xor(s, o);
  const float mean = s * (1.f / 256.f);
  float ss = 0.f;
#pragma unroll
  for (int c4 = 0; c4 < 4; ++c4) {
    const float d0 = v[c4].x - mean, d1 = v[c4].y - mean;
    const float d2 = v[c4].z - mean, d3 = v[c4].w - mean;
    ss += d0 * d0 + d1 * d1 + d2 * d2 + d3 * d3;
  }
#pragma unroll
  for (int o = 1; o < 16; o <<= 1) ss += __shfl_xor(ss, o);
  const float rstd = rsqrtf(ss * (1.f / 256.f) + 1e-5f);

#pragma unroll
  for (int c4 = 0; c4 < 4; ++c4) {
    const int col = c4 * 64 + li * 4;
    const float4 gv = *(const float4*)&g[col];
    const float4 bv = *(const float4*)&b[col];
    float4 o4;
    o4.x = (v[c4].x - mean) * rstd * gv.x + bv.x;
    o4.y = (v[c4].y - mean) * rstd * gv.y + bv.y;
    o4.z = (v[c4].z - mean) * rstd * gv.z + bv.z;
    o4.w = (v[c4].w - mean) * rstd * gv.w + bv.w;
    if (outf) *(float4*)(outf + rowoff + col) = o4;
    if (out16) {
      ushort4 o;
      o.x = f2h(o4.x); o.y = f2h(o4.y); o.z = f2h(o4.z); o.w = f2h(o4.w);
      *(ushort4*)(out16 + rowoff + col) = o;
    }
  }
}

// ---------------------------------------------------------------------------
// Deformable sampling v5: packed f16 accum + ushort indices (17.4 KB LDS ->
// 8 blk/CU) + XCD-aware block swizzle (value slab per XCD ~= L2-resident).
// ---------------------------------------------------------------------------
__global__ __launch_bounds__(256) void samp_k(
    const unsigned short* __restrict__ value16, const unsigned short* __restrict__ fused16,
    const float* __restrict__ ref, unsigned short* __restrict__ att16)
{
  // XCD swizzle: 2720 blocks, 8 XCDs, 340 blocks/XCD contiguous work chunk.
  const int b = blockIdx.x;
  const int wg = (b & 7) * 340 + (b >> 3);
  const int tok0 = wg * 8;

  __shared__ half4v swv[8][136];   // 8.7 KB: 4 corner weights (f16)
  __shared__ uint2  siv[8][136];   // 8.7 KB: 4 corner indices (ushort4 packed)
  const int t = threadIdx.x;
  const _Float16* fh = (const _Float16*)fused16;

#pragma unroll
  for (int it = 0; it < 4; ++it) {
    const int idx = it * 256 + t;
    const int ti = idx >> 7;
    const int e  = idx & 127;              // h*16 + lvl*4 + p
    const int tok = tok0 + ti;
    const int h = e >> 4;
    const int lvl = (e >> 2) & 3;
    const int HW[4] = {64, 32, 16, 8};
    const int LS[4] = {0, 4096, 5120, 5376};
    const int Wl = HW[lvl];

    const float lg = (float)fh[(size_t)tok * 384 + 256 + e];
    float mx = lg;
#pragma unroll
    for (int o = 1; o < 16; o <<= 1) mx = fmaxf(mx, __shfl_xor(mx, o, 16));
    const float ex = __expf(lg - mx);
    float sm = ex;
#pragma unroll
    for (int o = 1; o < 16; o <<= 1) sm += __shfl_xor(sm, o, 16);
    const float a = ex / sm;

    const float ox = (float)fh[(size_t)tok * 384 + e * 2 + 0];
    const float oy = (float)fh[(size_t)tok * 384 + e * 2 + 1];
    const float rx = ref[(size_t)tok * 8 + lvl * 2 + 0];
    const float ry = ref[(size_t)tok * 8 + lvl * 2 + 1];
    const float x = rx * (float)Wl + ox - 0.5f;
    const float y = ry * (float)Wl + oy - 0.5f;
    const float x0f = floorf(x), y0f = floorf(y);
    const float fx = x - x0f, fy = y - y0f;
    const int x0 = (int)x0f, y0 = (int)y0f;

    const int xi1 = x0 + 1, yi1 = y0 + 1;
    const float wx0 = 1.f - fx, wx1 = fx, wy0 = 1.f - fy, wy1 = fy;
    const int xc0 = min(max(x0, 0), Wl - 1), xc1 = min(max(xi1, 0), Wl - 1);
    const int yc0 = min(max(y0, 0), Wl - 1), yc1 = min(max(yi1, 0), Wl - 1);
    const bool vx0 = (x0 >= 0) & (x0 < Wl), vx1 = (xi1 >= 0) & (xi1 < Wl);
    const bool vy0 = (y0 >= 0) & (y0 < Wl), vy1 = (yi1 >= 0) & (yi1 < Wl);
    half4v hw;
    hw.x = (_Float16)((vx0 & vy0) ? a * wx0 * wy0 : 0.f);
    hw.y = (_Float16)((vx1 & vy0) ? a * wx1 * wy0 : 0.f);
    hw.z = (_Float16)((vx0 & vy1) ? a * wx0 * wy1 : 0.f);
    hw.w = (_Float16)((vx1 & vy1) ? a * wx1 * wy1 : 0.f);
    const unsigned i00 = (unsigned)(LS[lvl] + yc0 * Wl + xc0);
    const unsigned i01 = (unsigned)(LS[lvl] + yc0 * Wl + xc1);
    const unsigned i10 = (unsigned)(LS[lvl] + yc1 * Wl + xc0);
    const unsigned i11 = (unsigned)(LS[lvl] + yc1 * Wl + xc1);
    uint2 io;
    io.x = i00 | (i01 << 16);
    io.y = i10 | (i11 << 16);
    const int sl = e + h;
    swv[ti][sl] = hw;
    siv[ti][sl] = io;
  }
  __syncthreads();

  const int wave = t >> 6, lane = t & 63;
  const int ti = wave * 2 + (lane >> 5);
  const int h = (lane >> 2) & 7, dg = lane & 3;
  const int tok = tok0 + ti;
  const int vbase = (tok0 / LQ_) * LQ_;              // block-uniform (tok0%8==0)
  const char* vb = (const char*)(value16 + (size_t)vbase * 256);
  const int laneoff = h * 64 + dg * 16;
  h2v a0 = {0, 0}, a1 = {0, 0}, a2 = {0, 0}, a3 = {0, 0};
  const int ebase = h * 17;

#pragma unroll 4
  for (int p = 0; p < 16; ++p) {
    const half4v hw = swv[ti][ebase + p];
    const uint2 io = siv[ti][ebase + p];
    const int o00 = (int)((io.x & 0xFFFFu) << 9) + laneoff;
    const int o01 = (int)((io.x >> 16) << 9) + laneoff;
    const int o10 = (int)((io.y & 0xFFFFu) << 9) + laneoff;
    const int o11 = (int)((io.y >> 16) << 9) + laneoff;
    const uint4 u0 = *(const uint4*)(vb + o00);
    const uint4 u1 = *(const uint4*)(vb + o01);
    const uint4 u2 = *(const uint4*)(vb + o10);
    const uint4 u3 = *(const uint4*)(vb + o11);
#define CORNER(U, WI) {                                            \
    const h2v w2 = __builtin_shufflevector(hw, hw, WI, WI);        \
    a0 += w2 * __builtin_bit_cast(h2v, U.x);                       \
    a1 += w2 * __builtin_bit_cast(h2v, U.y);                       \
    a2 += w2 * __builtin_bit_cast(h2v, U.z);                       \
    a3 += w2 * __builtin_bit_cast(h2v, U.w); }
    CORNER(u0, 0) CORNER(u1, 1) CORNER(u2, 2) CORNER(u3, 3)
#undef CORNER
  }

  uint4 o;
  o.x = __builtin_bit_cast(unsigned, a0);
  o.y = __builtin_bit_cast(unsigned, a1);
  o.z = __builtin_bit_cast(unsigned, a2);
  o.w = __builtin_bit_cast(unsigned, a3);
  *(uint4*)(att16 + (size_t)tok * 256 + h * 32 + dg * 8) = o;
}

// ---------------------------------------------------------------------------
extern "C" void kernel_launch(void* const* d_in, const int* in_sizes, int n_in,
                              void* d_out, int out_size, void* d_ws, size_t ws_size,
                              hipStream_t stream)
{
  const float* src   = (const float*)d_in[0];
  const float* pos   = (const float*)d_in[1];
  const float* ref   = (const float*)d_in[2];
  const float* Wv    = (const float*)d_in[5];
  const float* bv    = (const float*)d_in[6];
  const float* Woff  = (const float*)d_in[7];
  const float* boff  = (const float*)d_in[8];
  const float* Wattn = (const float*)d_in[9];
  const float* battn = (const float*)d_in[10];
  const float* Wout  = (const float*)d_in[11];
  const float* bout  = (const float*)d_in[12];
  const float* g1    = (const float*)d_in[13];
  const float* b1    = (const float*)d_in[14];
  const float* W1    = (const float*)d_in[15];
  const float* bb1   = (const float*)d_in[16];
  const float* W2    = (const float*)d_in[17];
  const float* bb2   = (const float*)d_in[18];
  const float* g3    = (const float*)d_in[19];
  const float* b3    = (const float*)d_in[20];

  float* out = (float*)d_out;
  char* ws = (char*)d_ws;
  const size_t M = M_TOK;

  float* bufA = (float*)ws;                              // f32 M*256: value16 alias -> sxy f32
  unsigned short* fused16 = (unsigned short*)(ws + M * 256 * 4);  // f16 M*384
  unsigned short* bufE = fused16 + M * 384;              // f16 M*256: s16 -> att16 -> h16
  unsigned short* bufF = bufE + M * 256;                 // f16 M*256: q16 -> sxy16
  unsigned short* bufG = bufF + M * 256;                 // f16 weights (360448)
  unsigned short* value16 = (unsigned short*)bufA;       // f16 M*256, ends at samp

  unsigned short* WvT     = bufG + 0;
  unsigned short* WfusedT = bufG + 65536;
  unsigned short* WoutT   = bufG + 163840;
  unsigned short* W1T     = bufG + 229376;
  unsigned short* W2T     = bufG + 294912;

  const dim3 blk(256);

  prep_k<<<dim3(6848), blk, 0, stream>>>(src, pos, Wv, Woff, Wattn, Wout, W1, W2,
                                         bufE, bufF, bufG);
  // value16 = s16@WvT+bv ; fused16 = q16@[Woff|Wattn]+[boff|battn]
  gemm_qkv_k<<<dim3(170, 5), blk, 0, stream>>>(bufE, bufF, WvT, WfusedT,
                                               bv, boff, battn, value16, fused16);
  // sampling (with in-kernel softmax) -> att16
  samp_k<<<dim3(2720), blk, 0, stream>>>(value16, fused16, ref, bufE);
  // sxy = LN(att @ Wout + bout + src) -> bufA f32 + bufF f16
  gemm_ln_k<<<dim3(680), dim3(512), 0, stream>>>(bufE, WoutT, bout, src, g1, b1, bufA, bufF);
  // h16 = f16(relu(sxy @ W1 + bb1))
  gemm16_k<<<dim3(170, 2), blk, 0, stream>>>(bufF, W1T, bb1, bufE, 256, 1);
  // out = LN(h @ W2 + bb2 + sxy)
  gemm_ln_k<<<dim3(680), dim3(512), 0, stream>>>(bufE, W2T, bb2, bufA, g3, b3, out, nullptr);
}